// Round 1
// baseline (596.973 us; speedup 1.0000x reference)
//
#include <hip/hip_runtime.h>
#include <cmath>

#define BB 16
#define NN 1024
#define KK1 205
#define KK2 42
#define CAP 96

// ---------------- single pass over adj: degree, bitmask, neighbor lists ----
__global__ void k_deg_csr(const float* __restrict__ adj, float* __restrict__ dis0,
                          int* __restrict__ ncnt, int* __restrict__ nbr,
                          unsigned long long* __restrict__ mask) {
  int row = blockIdx.x * 4 + (threadIdx.x >> 6);   // one wave per row
  int lane = threadIdx.x & 63;
  const float* ar = adj + (size_t)row * NN;
  int base = 0;
  for (int c = 0; c < 16; ++c) {
    float v = ar[c * 64 + lane];
    unsigned long long m = __ballot(v != 0.0f);
    if (lane == c) mask[(size_t)row * 16 + c] = m;
    if (v != 0.0f) {
      int pos = base + __popcll(m & ((1ull << lane) - 1ull));
      if (pos < CAP) nbr[(size_t)row * CAP + pos] = c * 64 + lane;
    }
    base += __popcll(m);
  }
  if (lane == 0) {
    ncnt[row] = base < CAP ? base : CAP;
    dis0[row] = rsqrtf((float)base + 2.0f);
  }
}

// ---------------- dxw = dis * (x @ Wd0), IN_DIM=3 ---------------------------
__global__ void k_xw3(const float* __restrict__ x, const float* __restrict__ W,
                      const float* __restrict__ dis, float* __restrict__ out) {
  int idx = blockIdx.x * 256 + threadIdx.x;       // BB*NN*32
  int f = idx & 31; int node = idx >> 5;
  const float* xr = x + (size_t)node * 3;
  float s = xr[0] * W[f] + xr[1] * W[32 + f] + xr[2] * W[64 + f];
  out[idx] = s * dis[node];
}

// ---------------- t = dis * (in @ W), 32x32 --------------------------------
__global__ void k_xw32(const float* __restrict__ in, const float* __restrict__ W,
                       const float* __restrict__ dis, float* __restrict__ out) {
  int idx = blockIdx.x * 256 + threadIdx.x;
  int f = idx & 31; int node = idx >> 5;
  const float* xr = in + (size_t)node * 32;
  float s = 0.f;
#pragma unroll
  for (int k = 0; k < 32; ++k) s += xr[k] * W[k * 32 + f];
  out[idx] = s * dis[node];
}

// ---------------- sparse GCN apply (binary adjacency) ----------------------
template<bool RELU>
__global__ void k_spmm(const float* __restrict__ dxw, const float* __restrict__ dis,
                       const int* __restrict__ ncnt, const int* __restrict__ nbr,
                       const float* __restrict__ bias, float* __restrict__ out) {
  int tid = threadIdx.x;
  int g = tid >> 5, f = tid & 31;
  int node = blockIdx.x * 8 + g;                  // node = b*NN + i
  int b = node >> 10;
  int cnt = ncnt[node];
  const int* lst = nbr + (size_t)node * CAP;
  float acc = 0.f;
  for (int k = 0; k < cnt; ++k) {
    int j = lst[k];
    acc += dxw[(size_t)((b << 10) + j) * 32 + f];
  }
  acc += 2.0f * dxw[(size_t)node * 32 + f];
  float r = dis[node] * acc + bias[f];
  if (RELU) r = fmaxf(r, 0.f);
  out[(size_t)node * 32 + f] = r;
}

// ---------------- top-k: scores + bitonic sort (desc value, asc index) -----
template<int MPAD>
__global__ void k_topk(const float* __restrict__ h, const float* __restrict__ p,
                       int M, int K, int* __restrict__ perm, float* __restrict__ vals) {
  __shared__ float sval[MPAD];
  __shared__ int   sidx[MPAD];
  int b = blockIdx.x, t = threadIdx.x;
  float nn = 0.f;
#pragma unroll
  for (int k = 0; k < 32; ++k) nn += p[k] * p[k];
  float v;
  if (t < M) {
    const float* hr = h + (size_t)(b * M + t) * 32;
    float d = 0.f;
#pragma unroll
    for (int k = 0; k < 32; ++k) d += hr[k] * p[k];
    v = tanhf(d / sqrtf(nn));
  } else {
    v = -INFINITY;
  }
  sval[t] = v; sidx[t] = t;
  __syncthreads();
  for (int k = 2; k <= MPAD; k <<= 1) {
    for (int j = k >> 1; j > 0; j >>= 1) {
      int ixj = t ^ j;
      if (ixj > t) {
        float va = sval[t], vb = sval[ixj];
        int ia = sidx[t], ib = sidx[ixj];
        bool aBefore = (va > vb) || (va == vb && ia < ib);
        bool up = ((t & k) == 0);
        if (up != aBefore) { sval[t] = vb; sidx[t] = ib; sval[ixj] = va; sidx[ixj] = ia; }
      }
      __syncthreads();
    }
  }
  if (t < K) { perm[b * K + t] = sidx[t]; vals[b * K + t] = sval[t]; }
}

// ---------------- pooled gather: hp = h[perm] * vals -----------------------
__global__ void k_gather(const float* __restrict__ h, const int* __restrict__ perm,
                         const float* __restrict__ vals, int M, int K,
                         float* __restrict__ hp) {
  int idx = blockIdx.x * 256 + threadIdx.x;       // BB*K*32
  int f = idx & 31; int q = idx >> 5;
  int k = q % K, b = q / K;
  int src = perm[b * K + k];
  hp[idx] = h[(size_t)(b * M + src) * 32 + f] * vals[b * K + k];
}

// ---------------- A1 = augment(adj)[perm1,perm1] via bitsets ---------------
__global__ void k_buildA1(const unsigned long long* __restrict__ mask,
                          const int* __restrict__ perm1, float* __restrict__ A1) {
  __shared__ unsigned long long sm[KK1 * 16];
  __shared__ int sp[KK1];
  int b = blockIdx.x, t = threadIdx.x;
  if (t < KK1) sp[t] = perm1[b * KK1 + t];
  __syncthreads();
  for (int q = t; q < KK1 * 16; q += 256) {
    int i = q >> 4, w = q & 15;
    sm[q] = mask[((size_t)(b * NN + sp[i])) * 16 + w];
  }
  __syncthreads();
  if (t < KK1) {
    unsigned long long r[16];
#pragma unroll
    for (int w = 0; w < 16; ++w) r[w] = sm[t * 16 + w];
    for (int j = 0; j < KK1; ++j) {
      int cnt = 0;
#pragma unroll
      for (int w = 0; w < 16; ++w) cnt += __popcll(r[w] & sm[j * 16 + w]);
      int pj = sp[j];
      float edge = (float)((r[pj >> 6] >> (pj & 63)) & 1ull);
      float v = (j == t) ? 0.f : ((float)cnt + 2.f * edge);
      A1[((size_t)(b * KK1) + t) * KK1 + j] = v;
    }
  }
}

// ---------------- dis = rsqrt(2 + rowsum(A)) -------------------------------
__global__ void k_rowdis(const float* __restrict__ A, int M, int rowsTotal,
                         float* __restrict__ dis) {
  int g = threadIdx.x >> 5, lane = threadIdx.x & 31;
  int row = blockIdx.x * 8 + g;
  if (row >= rowsTotal) return;
  const float* ar = A + (size_t)row * M;
  float s = 0.f;
  for (int j = lane; j < M; j += 32) s += ar[j];
#pragma unroll
  for (int o = 16; o; o >>= 1) s += __shfl_xor(s, o, 32);
  if (lane == 0) dis[row] = rsqrtf(s + 2.0f);
}

// ---------------- dense GCN apply (weighted A, small M) --------------------
template<bool RELU>
__global__ void k_dense_apply(const float* __restrict__ A, const float* __restrict__ t,
                              const float* __restrict__ dis, const float* __restrict__ bias,
                              int M, int rowsTotal, float* __restrict__ out) {
  int g = threadIdx.x >> 5, f = threadIdx.x & 31;
  int row = blockIdx.x * 8 + g;
  if (row >= rowsTotal) return;
  int b = row / M; int i = row - b * M;
  const float* Ar = A + (size_t)row * M;
  const float* tb = t + (size_t)b * M * 32;
  float acc = 0.f;
  for (int j = 0; j < M; ++j) acc += Ar[j] * tb[j * 32 + f];
  acc += 2.0f * tb[i * 32 + f];
  float r = dis[row] * acc + bias[f];
  if (RELU) r = fmaxf(r, 0.f);
  out[(size_t)row * 32 + f] = r;
}

// ---------------- A2 = augment(A1)[perm2,perm2] (dense dot) ----------------
__global__ void k_buildA2(const float* __restrict__ A1, const int* __restrict__ perm2,
                          float* __restrict__ A2) {
  int row = blockIdx.x;                            // b*KK2 + i
  int b = row / KK2, i = row - b * KK2;
  int g = threadIdx.x >> 5, lane = threadIdx.x & 31;
  int pi = perm2[b * KK2 + i];
  const float* Ri = A1 + ((size_t)(b * KK1 + pi)) * KK1;
  for (int j = g; j < KK2; j += 8) {
    int pj = perm2[b * KK2 + j];
    const float* Rj = A1 + ((size_t)(b * KK1 + pj)) * KK1;
    float s = 0.f;
    for (int k = lane; k < KK1; k += 32) s += Ri[k] * Rj[k];
#pragma unroll
    for (int o = 16; o; o >>= 1) s += __shfl_xor(s, o, 32);
    if (lane == 0) {
      float v = (i == j) ? 0.f : (s + 2.0f * Ri[pj]);
      A2[((size_t)(b * KK2) + i) * KK2 + j] = v;
    }
  }
}

// ---------------- copy & scatter-add ---------------------------------------
__global__ void k_copy(const float* __restrict__ in, float* __restrict__ out) {
  int idx = blockIdx.x * 256 + threadIdx.x;
  out[idx] = in[idx];
}
__global__ void k_scatter_add(const float* __restrict__ src, const int* __restrict__ perm,
                              int K, int Mdst, float* __restrict__ dst) {
  int idx = blockIdx.x * 256 + threadIdx.x;       // BB*K*32
  int f = idx & 31; int q = idx >> 5;
  int k = q % K, b = q / K;
  int d = perm[b * K + k];
  dst[((size_t)(b * Mdst) + d) * 32 + f] += src[idx];
}

// ---------------- batchnorm stats ------------------------------------------
__global__ void k_bnstats(const float* __restrict__ h, float* __restrict__ mean,
                          float* __restrict__ var) {
  int f = blockIdx.x, t = threadIdx.x;
  float s = 0.f, sq = 0.f;
  for (int i = t; i < BB * NN; i += 256) {
    float v = h[(size_t)i * 32 + f];
    s += v; sq += v * v;
  }
  __shared__ float ss[256], sv[256];
  ss[t] = s; sv[t] = sq; __syncthreads();
  for (int o = 128; o; o >>= 1) {
    if (t < o) { ss[t] += ss[t + o]; sv[t] += sv[t + o]; }
    __syncthreads();
  }
  if (t == 0) {
    float m = ss[0] / (float)(BB * NN);
    mean[f] = m;
    var[f] = sv[0] / (float)(BB * NN) - m * m;
  }
}

// ---------------- BN + 3-layer MLP head ------------------------------------
__global__ void k_mlp(const float* __restrict__ h, const float* __restrict__ mean,
                      const float* __restrict__ var, const float* __restrict__ gamma,
                      const float* __restrict__ beta,
                      const float* __restrict__ W1, const float* __restrict__ b1,
                      const float* __restrict__ W2, const float* __restrict__ b2,
                      const float* __restrict__ W3, const float* __restrict__ b3,
                      float* __restrict__ out) {
  int node = blockIdx.x * 256 + threadIdx.x;      // BB*NN
  const float* hr = h + (size_t)node * 32;
  float hn[32];
#pragma unroll
  for (int k = 0; k < 32; ++k)
    hn[k] = (hr[k] - mean[k]) * (1.0f / sqrtf(var[k] + 1e-5f)) * gamma[k] + beta[k];
  float r1[32];
#pragma unroll
  for (int f = 0; f < 32; ++f) {
    float s = b1[f];
#pragma unroll
    for (int k = 0; k < 32; ++k) s += hn[k] * W1[k * 32 + f];
    r1[f] = s > 0.f ? s : 0.01f * s;
  }
  float r2[32];
#pragma unroll
  for (int f = 0; f < 32; ++f) {
    float s = b2[f];
#pragma unroll
    for (int k = 0; k < 32; ++k) s += r1[k] * W2[k * 32 + f];
    r2[f] = s > 0.f ? s : 0.01f * s;
  }
  float r3[4];
#pragma unroll
  for (int c = 0; c < 4; ++c) {
    float s = b3[c];
#pragma unroll
    for (int k = 0; k < 32; ++k) s += r2[k] * W3[k * 4 + c];
    r3[c] = s;
  }
  r3[0] = 1.0f / (1.0f + expf(-r3[0]));
  float* o = out + (size_t)node * 4;
  o[0] = r3[0]; o[1] = r3[1]; o[2] = r3[2]; o[3] = r3[3];
}

extern "C" void kernel_launch(void* const* d_in, const int* in_sizes, int n_in,
                              void* d_out, int out_size, void* d_ws, size_t ws_size,
                              hipStream_t stream) {
  const float* x    = (const float*)d_in[0];
  const float* adj  = (const float*)d_in[1];
  const float* Wd0  = (const float*)d_in[2];
  const float* bd0  = (const float*)d_in[3];
  const float* Wd1  = (const float*)d_in[4];
  const float* bd1  = (const float*)d_in[5];
  const float* Wd2  = (const float*)d_in[6];
  const float* bd2  = (const float*)d_in[7];
  const float* Wu0  = (const float*)d_in[8];
  const float* bu0  = (const float*)d_in[9];
  const float* Wu1  = (const float*)d_in[10];
  const float* bu1  = (const float*)d_in[11];
  const float* p1   = (const float*)d_in[12];
  const float* p2   = (const float*)d_in[13];
  const float* gamma= (const float*)d_in[14];
  const float* beta = (const float*)d_in[15];
  const float* W1   = (const float*)d_in[16];
  const float* b1   = (const float*)d_in[17];
  const float* W2   = (const float*)d_in[18];
  const float* b2   = (const float*)d_in[19];
  const float* W3   = (const float*)d_in[20];
  const float* b3   = (const float*)d_in[21];
  float* out = (float*)d_out;

  char* w = (char*)d_ws;
  auto alloc = [&](size_t bytes) -> void* {
    void* p = (void*)w;
    w += (bytes + 255) & ~(size_t)255;
    return p;
  };
  float* dis0 = (float*)alloc(BB * NN * 4);
  int*   ncnt = (int*)alloc(BB * NN * 4);
  int*   nbr  = (int*)alloc((size_t)BB * NN * CAP * 4);
  unsigned long long* mask = (unsigned long long*)alloc((size_t)BB * NN * 16 * 8);
  float* dxw  = (float*)alloc((size_t)BB * NN * 32 * 4);
  float* h0   = (float*)alloc((size_t)BB * NN * 32 * 4);
  int*   perm1= (int*)alloc(BB * KK1 * 4);
  float* vals1= (float*)alloc(BB * KK1 * 4);
  float* hp1  = (float*)alloc((size_t)BB * KK1 * 32 * 4);
  float* A1   = (float*)alloc((size_t)BB * KK1 * KK1 * 4);
  float* dis1 = (float*)alloc(BB * KK1 * 4);
  float* t1   = (float*)alloc((size_t)BB * KK1 * 32 * 4);
  float* h1   = (float*)alloc((size_t)BB * KK1 * 32 * 4);
  int*   perm2= (int*)alloc(BB * KK2 * 4);
  float* vals2= (float*)alloc(BB * KK2 * 4);
  float* hp2  = (float*)alloc((size_t)BB * KK2 * 32 * 4);
  float* A2   = (float*)alloc((size_t)BB * KK2 * KK2 * 4);
  float* dis2 = (float*)alloc(BB * KK2 * 4);
  float* t2   = (float*)alloc((size_t)BB * KK2 * 32 * 4);
  float* h2   = (float*)alloc((size_t)BB * KK2 * 32 * 4);
  float* u1   = (float*)alloc((size_t)BB * KK1 * 32 * 4);
  float* hu0  = (float*)alloc((size_t)BB * KK1 * 32 * 4);
  float* u0   = (float*)alloc((size_t)BB * NN * 32 * 4);
  float* hfin = (float*)alloc((size_t)BB * NN * 32 * 4);
  float* bmean= (float*)alloc(32 * 4);
  float* bvar = (float*)alloc(32 * 4);

  const int TOT_N32  = BB * NN * 32;     // 524288
  const int TOT_K132 = BB * KK1 * 32;    // 104960
  const int TOT_K232 = BB * KK2 * 32;    // 21504

  // 1) single adj pass: degree + bitmask + CSR
  k_deg_csr<<<BB * NN / 4, 256, 0, stream>>>(adj, dis0, ncnt, nbr, mask);
  // 2) GCN0: dxw = dis0*(x@Wd0);  h0 = relu(spmm)
  k_xw3<<<TOT_N32 / 256, 256, 0, stream>>>(x, Wd0, dis0, dxw);
  k_spmm<true><<<BB * NN / 8, 256, 0, stream>>>(dxw, dis0, ncnt, nbr, bd0, h0);
  // 3) top-k pool 1
  k_topk<1024><<<BB, 1024, 0, stream>>>(h0, p1, NN, KK1, perm1, vals1);
  k_gather<<<TOT_K132 / 256, 256, 0, stream>>>(h0, perm1, vals1, NN, KK1, hp1);
  k_buildA1<<<BB, 256, 0, stream>>>(mask, perm1, A1);
  k_rowdis<<<(BB * KK1 + 7) / 8, 256, 0, stream>>>(A1, KK1, BB * KK1, dis1);
  // 4) GCN1 (level-1 dense)
  k_xw32<<<TOT_K132 / 256, 256, 0, stream>>>(hp1, Wd1, dis1, t1);
  k_dense_apply<true><<<(BB * KK1 + 7) / 8, 256, 0, stream>>>(A1, t1, dis1, bd1, KK1, BB * KK1, h1);
  // 5) top-k pool 2
  k_topk<256><<<BB, 256, 0, stream>>>(h1, p2, KK1, KK2, perm2, vals2);
  k_gather<<<TOT_K232 / 256, 256, 0, stream>>>(h1, perm2, vals2, KK1, KK2, hp2);
  k_buildA2<<<BB * KK2, 256, 0, stream>>>(A1, perm2, A2);
  k_rowdis<<<(BB * KK2 + 7) / 8, 256, 0, stream>>>(A2, KK2, BB * KK2, dis2);
  // 6) GCN2 (level-2 dense)
  k_xw32<<<TOT_K232 / 256, 256, 0, stream>>>(hp2, Wd2, dis2, t2);
  k_dense_apply<true><<<(BB * KK2 + 7) / 8, 256, 0, stream>>>(A2, t2, dis2, bd2, KK2, BB * KK2, h2);
  // 7) unpool 2 + up-GCN (level-1)
  k_copy<<<TOT_K132 / 256, 256, 0, stream>>>(h1, u1);
  k_scatter_add<<<TOT_K232 / 256, 256, 0, stream>>>(h2, perm2, KK2, KK1, u1);
  k_xw32<<<TOT_K132 / 256, 256, 0, stream>>>(u1, Wu0, dis1, t1);
  k_dense_apply<true><<<(BB * KK1 + 7) / 8, 256, 0, stream>>>(A1, t1, dis1, bu0, KK1, BB * KK1, hu0);
  // 8) unpool 1 + final GCN (level-0 sparse, no relu)
  k_copy<<<TOT_N32 / 256, 256, 0, stream>>>(h0, u0);
  k_scatter_add<<<TOT_K132 / 256, 256, 0, stream>>>(hu0, perm1, KK1, NN, u0);
  k_xw32<<<TOT_N32 / 256, 256, 0, stream>>>(u0, Wu1, dis0, dxw);
  k_spmm<false><<<BB * NN / 8, 256, 0, stream>>>(dxw, dis0, ncnt, nbr, bu1, hfin);
  // 9) batchnorm + MLP head
  k_bnstats<<<32, 256, 0, stream>>>(hfin, bmean, bvar);
  k_mlp<<<BB * NN / 256, 256, 0, stream>>>(hfin, bmean, bvar, gamma, beta,
                                           W1, b1, W2, b2, W3, b3, out);
}

// Round 2
// 521.251 us; speedup vs baseline: 1.1453x; 1.1453x over previous
//
#include <hip/hip_runtime.h>
#include <cmath>

#define BB 16
#define NN 1024
#define KK1 205
#define KK2 42
#define CAP 96

// ---------------- single pass over adj: degree, bitmask, neighbor lists ----
__global__ void k_deg_csr(const float* __restrict__ adj, float* __restrict__ dis0,
                          int* __restrict__ ncnt, int* __restrict__ nbr,
                          unsigned long long* __restrict__ mask) {
  int row = blockIdx.x * 4 + (threadIdx.x >> 6);   // one wave per row
  int lane = threadIdx.x & 63;
  const float* ar = adj + (size_t)row * NN;
  int base = 0;
  for (int c = 0; c < 16; ++c) {
    float v = ar[c * 64 + lane];
    unsigned long long m = __ballot(v != 0.0f);
    if (lane == c) mask[(size_t)row * 16 + c] = m;
    if (v != 0.0f) {
      int pos = base + __popcll(m & ((1ull << lane) - 1ull));
      if (pos < CAP) nbr[(size_t)row * CAP + pos] = c * 64 + lane;
    }
    base += __popcll(m);
  }
  if (lane == 0) {
    ncnt[row] = base < CAP ? base : CAP;
    dis0[row] = rsqrtf((float)base + 2.0f);
  }
}

// ---------------- dxw = dis * (x @ Wd0), IN_DIM=3 ---------------------------
__global__ void k_xw3(const float* __restrict__ x, const float* __restrict__ W,
                      const float* __restrict__ dis, float* __restrict__ out) {
  int idx = blockIdx.x * 256 + threadIdx.x;       // BB*NN*32
  int f = idx & 31; int node = idx >> 5;
  const float* xr = x + (size_t)node * 3;
  float s = xr[0] * W[f] + xr[1] * W[32 + f] + xr[2] * W[64 + f];
  out[idx] = s * dis[node];
}

// ---------------- t = dis * (in @ W), 32x32 --------------------------------
__global__ void k_xw32(const float* __restrict__ in, const float* __restrict__ W,
                       const float* __restrict__ dis, float* __restrict__ out) {
  int idx = blockIdx.x * 256 + threadIdx.x;
  int f = idx & 31; int node = idx >> 5;
  const float* xr = in + (size_t)node * 32;
  float s = 0.f;
#pragma unroll
  for (int k = 0; k < 32; ++k) s += xr[k] * W[k * 32 + f];
  out[idx] = s * dis[node];
}

// ---------------- sparse GCN apply (binary adjacency) ----------------------
template<bool RELU>
__global__ void k_spmm(const float* __restrict__ dxw, const float* __restrict__ dis,
                       const int* __restrict__ ncnt, const int* __restrict__ nbr,
                       const float* __restrict__ bias, float* __restrict__ out) {
  int tid = threadIdx.x;
  int g = tid >> 5, f = tid & 31;
  int node = blockIdx.x * 8 + g;                  // node = b*NN + i
  int b = node >> 10;
  int cnt = ncnt[node];
  const int* lst = nbr + (size_t)node * CAP;
  float acc = 0.f;
  for (int k = 0; k < cnt; ++k) {
    int j = lst[k];
    acc += dxw[(size_t)((b << 10) + j) * 32 + f];
  }
  acc += 2.0f * dxw[(size_t)node * 32 + f];
  float r = dis[node] * acc + bias[f];
  if (RELU) r = fmaxf(r, 0.f);
  out[(size_t)node * 32 + f] = r;
}

// ---------------- top-k: scores + bitonic sort (desc value, asc index) -----
template<int MPAD>
__global__ void k_topk(const float* __restrict__ h, const float* __restrict__ p,
                       int M, int K, int* __restrict__ perm, float* __restrict__ vals) {
  __shared__ float sval[MPAD];
  __shared__ int   sidx[MPAD];
  int b = blockIdx.x, t = threadIdx.x;
  float nn = 0.f;
#pragma unroll
  for (int k = 0; k < 32; ++k) nn += p[k] * p[k];
  float v;
  if (t < M) {
    const float* hr = h + (size_t)(b * M + t) * 32;
    float d = 0.f;
#pragma unroll
    for (int k = 0; k < 32; ++k) d += hr[k] * p[k];
    v = tanhf(d / sqrtf(nn));
  } else {
    v = -INFINITY;
  }
  sval[t] = v; sidx[t] = t;
  __syncthreads();
  for (int k = 2; k <= MPAD; k <<= 1) {
    for (int j = k >> 1; j > 0; j >>= 1) {
      int ixj = t ^ j;
      if (ixj > t) {
        float va = sval[t], vb = sval[ixj];
        int ia = sidx[t], ib = sidx[ixj];
        bool aBefore = (va > vb) || (va == vb && ia < ib);
        bool up = ((t & k) == 0);
        if (up != aBefore) { sval[t] = vb; sidx[t] = ib; sval[ixj] = va; sidx[ixj] = ia; }
      }
      __syncthreads();
    }
  }
  if (t < K) { perm[b * K + t] = sidx[t]; vals[b * K + t] = sval[t]; }
}

// ---------------- pooled gather: hp = h[perm] * vals -----------------------
__global__ void k_gather(const float* __restrict__ h, const int* __restrict__ perm,
                         const float* __restrict__ vals, int M, int K,
                         float* __restrict__ hp) {
  int idx = blockIdx.x * 256 + threadIdx.x;       // BB*K*32
  int f = idx & 31; int q = idx >> 5;
  int k = q % K, b = q / K;
  int src = perm[b * K + k];
  hp[idx] = h[(size_t)(b * M + src) * 32 + f] * vals[b * K + k];
}

// ---------------- A1 = augment(adj)[perm1,perm1] via bitsets ---------------
// one wave per output row; lanes stride over columns; fused dis1 row-sum.
// grid: BB * 52 blocks (4 rows/block), 256 threads.
__global__ void k_buildA1(const unsigned long long* __restrict__ mask,
                          const int* __restrict__ perm1, float* __restrict__ A1,
                          float* __restrict__ dis1) {
  __shared__ unsigned long long smT[16 * KK1];   // transposed: smT[w*KK1 + j]
  __shared__ int sp[KK1];
  int blk = blockIdx.x;
  int b = blk / 52, chunk = blk - b * 52;
  int t = threadIdx.x;
  if (t < KK1) sp[t] = perm1[b * KK1 + t];
  __syncthreads();
  for (int q = t; q < KK1 * 16; q += 256) {
    int i = q >> 4, w = q & 15;
    smT[w * KK1 + i] = mask[((size_t)(b * NN + sp[i])) * 16 + w];
  }
  __syncthreads();
  int wave = t >> 6, lane = t & 63;
  int i = chunk * 4 + wave;
  if (i < KK1) {
    unsigned long long r[16];
#pragma unroll
    for (int w = 0; w < 16; ++w) r[w] = smT[w * KK1 + i];
    float rowsum = 0.f;
    for (int j = lane; j < KK1; j += 64) {
      int cnt = 0;
#pragma unroll
      for (int w = 0; w < 16; ++w) cnt += __popcll(r[w] & smT[w * KK1 + j]);
      int pj = sp[j];
      float edge = (float)((r[pj >> 6] >> (pj & 63)) & 1ull);
      float v = (j == i) ? 0.f : ((float)cnt + 2.f * edge);
      A1[((size_t)(b * KK1) + i) * KK1 + j] = v;
      rowsum += v;
    }
#pragma unroll
    for (int o = 32; o; o >>= 1) rowsum += __shfl_xor(rowsum, o);
    if (lane == 0) dis1[b * KK1 + i] = rsqrtf(rowsum + 2.0f);
  }
}

// ---------------- dis = rsqrt(2 + rowsum(A)) -------------------------------
__global__ void k_rowdis(const float* __restrict__ A, int M, int rowsTotal,
                         float* __restrict__ dis) {
  int g = threadIdx.x >> 5, lane = threadIdx.x & 31;
  int row = blockIdx.x * 8 + g;
  if (row >= rowsTotal) return;
  const float* ar = A + (size_t)row * M;
  float s = 0.f;
  for (int j = lane; j < M; j += 32) s += ar[j];
#pragma unroll
  for (int o = 16; o; o >>= 1) s += __shfl_xor(s, o, 32);
  if (lane == 0) dis[row] = rsqrtf(s + 2.0f);
}

// ---------------- dense GCN apply (weighted A, small M) --------------------
template<bool RELU>
__global__ void k_dense_apply(const float* __restrict__ A, const float* __restrict__ t,
                              const float* __restrict__ dis, const float* __restrict__ bias,
                              int M, int rowsTotal, float* __restrict__ out) {
  int g = threadIdx.x >> 5, f = threadIdx.x & 31;
  int row = blockIdx.x * 8 + g;
  if (row >= rowsTotal) return;
  int b = row / M; int i = row - b * M;
  const float* Ar = A + (size_t)row * M;
  const float* tb = t + (size_t)b * M * 32;
  float acc = 0.f;
  for (int j = 0; j < M; ++j) acc += Ar[j] * tb[j * 32 + f];
  acc += 2.0f * tb[i * 32 + f];
  float r = dis[row] * acc + bias[f];
  if (RELU) r = fmaxf(r, 0.f);
  out[(size_t)row * 32 + f] = r;
}

// ---------------- A2 = augment(A1)[perm2,perm2] (dense dot) ----------------
__global__ void k_buildA2(const float* __restrict__ A1, const int* __restrict__ perm2,
                          float* __restrict__ A2) {
  int row = blockIdx.x;                            // b*KK2 + i
  int b = row / KK2, i = row - b * KK2;
  int g = threadIdx.x >> 5, lane = threadIdx.x & 31;
  int pi = perm2[b * KK2 + i];
  const float* Ri = A1 + ((size_t)(b * KK1 + pi)) * KK1;
  for (int j = g; j < KK2; j += 8) {
    int pj = perm2[b * KK2 + j];
    const float* Rj = A1 + ((size_t)(b * KK1 + pj)) * KK1;
    float s = 0.f;
    for (int k = lane; k < KK1; k += 32) s += Ri[k] * Rj[k];
#pragma unroll
    for (int o = 16; o; o >>= 1) s += __shfl_xor(s, o, 32);
    if (lane == 0) {
      float v = (i == j) ? 0.f : (s + 2.0f * Ri[pj]);
      A2[((size_t)(b * KK2) + i) * KK2 + j] = v;
    }
  }
}

// ---------------- copy & scatter-add ---------------------------------------
__global__ void k_copy(const float* __restrict__ in, float* __restrict__ out) {
  int idx = blockIdx.x * 256 + threadIdx.x;
  out[idx] = in[idx];
}
__global__ void k_scatter_add(const float* __restrict__ src, const int* __restrict__ perm,
                              int K, int Mdst, float* __restrict__ dst) {
  int idx = blockIdx.x * 256 + threadIdx.x;       // BB*K*32
  int f = idx & 31; int q = idx >> 5;
  int k = q % K, b = q / K;
  int d = perm[b * K + k];
  dst[((size_t)(b * Mdst) + d) * 32 + f] += src[idx];
}

// ---------------- batchnorm stats ------------------------------------------
__global__ void k_bnstats(const float* __restrict__ h, float* __restrict__ mean,
                          float* __restrict__ var) {
  int f = blockIdx.x, t = threadIdx.x;
  float s = 0.f, sq = 0.f;
  for (int i = t; i < BB * NN; i += 256) {
    float v = h[(size_t)i * 32 + f];
    s += v; sq += v * v;
  }
  __shared__ float ss[256], sv[256];
  ss[t] = s; sv[t] = sq; __syncthreads();
  for (int o = 128; o; o >>= 1) {
    if (t < o) { ss[t] += ss[t + o]; sv[t] += sv[t + o]; }
    __syncthreads();
  }
  if (t == 0) {
    float m = ss[0] / (float)(BB * NN);
    mean[f] = m;
    var[f] = sv[0] / (float)(BB * NN) - m * m;
  }
}

// ---------------- BN + 3-layer MLP head ------------------------------------
__global__ void k_mlp(const float* __restrict__ h, const float* __restrict__ mean,
                      const float* __restrict__ var, const float* __restrict__ gamma,
                      const float* __restrict__ beta,
                      const float* __restrict__ W1, const float* __restrict__ b1,
                      const float* __restrict__ W2, const float* __restrict__ b2,
                      const float* __restrict__ W3, const float* __restrict__ b3,
                      float* __restrict__ out) {
  int node = blockIdx.x * 256 + threadIdx.x;      // BB*NN
  const float* hr = h + (size_t)node * 32;
  float hn[32];
#pragma unroll
  for (int k = 0; k < 32; ++k)
    hn[k] = (hr[k] - mean[k]) * (1.0f / sqrtf(var[k] + 1e-5f)) * gamma[k] + beta[k];
  float r1[32];
#pragma unroll
  for (int f = 0; f < 32; ++f) {
    float s = b1[f];
#pragma unroll
    for (int k = 0; k < 32; ++k) s += hn[k] * W1[k * 32 + f];
    r1[f] = s > 0.f ? s : 0.01f * s;
  }
  float r2[32];
#pragma unroll
  for (int f = 0; f < 32; ++f) {
    float s = b2[f];
#pragma unroll
    for (int k = 0; k < 32; ++k) s += r1[k] * W2[k * 32 + f];
    r2[f] = s > 0.f ? s : 0.01f * s;
  }
  float r3[4];
#pragma unroll
  for (int c = 0; c < 4; ++c) {
    float s = b3[c];
#pragma unroll
    for (int k = 0; k < 32; ++k) s += r2[k] * W3[k * 4 + c];
    r3[c] = s;
  }
  r3[0] = 1.0f / (1.0f + expf(-r3[0]));
  float* o = out + (size_t)node * 4;
  o[0] = r3[0]; o[1] = r3[1]; o[2] = r3[2]; o[3] = r3[3];
}

extern "C" void kernel_launch(void* const* d_in, const int* in_sizes, int n_in,
                              void* d_out, int out_size, void* d_ws, size_t ws_size,
                              hipStream_t stream) {
  const float* x    = (const float*)d_in[0];
  const float* adj  = (const float*)d_in[1];
  const float* Wd0  = (const float*)d_in[2];
  const float* bd0  = (const float*)d_in[3];
  const float* Wd1  = (const float*)d_in[4];
  const float* bd1  = (const float*)d_in[5];
  const float* Wd2  = (const float*)d_in[6];
  const float* bd2  = (const float*)d_in[7];
  const float* Wu0  = (const float*)d_in[8];
  const float* bu0  = (const float*)d_in[9];
  const float* Wu1  = (const float*)d_in[10];
  const float* bu1  = (const float*)d_in[11];
  const float* p1   = (const float*)d_in[12];
  const float* p2   = (const float*)d_in[13];
  const float* gamma= (const float*)d_in[14];
  const float* beta = (const float*)d_in[15];
  const float* W1   = (const float*)d_in[16];
  const float* b1   = (const float*)d_in[17];
  const float* W2   = (const float*)d_in[18];
  const float* b2   = (const float*)d_in[19];
  const float* W3   = (const float*)d_in[20];
  const float* b3   = (const float*)d_in[21];
  float* out = (float*)d_out;

  char* w = (char*)d_ws;
  auto alloc = [&](size_t bytes) -> void* {
    void* p = (void*)w;
    w += (bytes + 255) & ~(size_t)255;
    return p;
  };
  float* dis0 = (float*)alloc(BB * NN * 4);
  int*   ncnt = (int*)alloc(BB * NN * 4);
  int*   nbr  = (int*)alloc((size_t)BB * NN * CAP * 4);
  unsigned long long* mask = (unsigned long long*)alloc((size_t)BB * NN * 16 * 8);
  float* dxw  = (float*)alloc((size_t)BB * NN * 32 * 4);
  float* h0   = (float*)alloc((size_t)BB * NN * 32 * 4);
  int*   perm1= (int*)alloc(BB * KK1 * 4);
  float* vals1= (float*)alloc(BB * KK1 * 4);
  float* hp1  = (float*)alloc((size_t)BB * KK1 * 32 * 4);
  float* A1   = (float*)alloc((size_t)BB * KK1 * KK1 * 4);
  float* dis1 = (float*)alloc(BB * KK1 * 4);
  float* t1   = (float*)alloc((size_t)BB * KK1 * 32 * 4);
  float* h1   = (float*)alloc((size_t)BB * KK1 * 32 * 4);
  int*   perm2= (int*)alloc(BB * KK2 * 4);
  float* vals2= (float*)alloc(BB * KK2 * 4);
  float* hp2  = (float*)alloc((size_t)BB * KK2 * 32 * 4);
  float* A2   = (float*)alloc((size_t)BB * KK2 * KK2 * 4);
  float* dis2 = (float*)alloc(BB * KK2 * 4);
  float* t2   = (float*)alloc((size_t)BB * KK2 * 32 * 4);
  float* h2   = (float*)alloc((size_t)BB * KK2 * 32 * 4);
  float* u1   = (float*)alloc((size_t)BB * KK1 * 32 * 4);
  float* hu0  = (float*)alloc((size_t)BB * KK1 * 32 * 4);
  float* u0   = (float*)alloc((size_t)BB * NN * 32 * 4);
  float* hfin = (float*)alloc((size_t)BB * NN * 32 * 4);
  float* bmean= (float*)alloc(32 * 4);
  float* bvar = (float*)alloc(32 * 4);

  const int TOT_N32  = BB * NN * 32;     // 524288
  const int TOT_K132 = BB * KK1 * 32;    // 104960
  const int TOT_K232 = BB * KK2 * 32;    // 21504

  // 1) single adj pass: degree + bitmask + CSR
  k_deg_csr<<<BB * NN / 4, 256, 0, stream>>>(adj, dis0, ncnt, nbr, mask);
  // 2) GCN0: dxw = dis0*(x@Wd0);  h0 = relu(spmm)
  k_xw3<<<TOT_N32 / 256, 256, 0, stream>>>(x, Wd0, dis0, dxw);
  k_spmm<true><<<BB * NN / 8, 256, 0, stream>>>(dxw, dis0, ncnt, nbr, bd0, h0);
  // 3) top-k pool 1
  k_topk<1024><<<BB, 1024, 0, stream>>>(h0, p1, NN, KK1, perm1, vals1);
  k_gather<<<TOT_K132 / 256, 256, 0, stream>>>(h0, perm1, vals1, NN, KK1, hp1);
  k_buildA1<<<BB * 52, 256, 0, stream>>>(mask, perm1, A1, dis1);
  // 4) GCN1 (level-1 dense)
  k_xw32<<<TOT_K132 / 256, 256, 0, stream>>>(hp1, Wd1, dis1, t1);
  k_dense_apply<true><<<(BB * KK1 + 7) / 8, 256, 0, stream>>>(A1, t1, dis1, bd1, KK1, BB * KK1, h1);
  // 5) top-k pool 2
  k_topk<256><<<BB, 256, 0, stream>>>(h1, p2, KK1, KK2, perm2, vals2);
  k_gather<<<TOT_K232 / 256, 256, 0, stream>>>(h1, perm2, vals2, KK1, KK2, hp2);
  k_buildA2<<<BB * KK2, 256, 0, stream>>>(A1, perm2, A2);
  k_rowdis<<<(BB * KK2 + 7) / 8, 256, 0, stream>>>(A2, KK2, BB * KK2, dis2);
  // 6) GCN2 (level-2 dense)
  k_xw32<<<TOT_K232 / 256, 256, 0, stream>>>(hp2, Wd2, dis2, t2);
  k_dense_apply<true><<<(BB * KK2 + 7) / 8, 256, 0, stream>>>(A2, t2, dis2, bd2, KK2, BB * KK2, h2);
  // 7) unpool 2 + up-GCN (level-1)
  k_copy<<<TOT_K132 / 256, 256, 0, stream>>>(h1, u1);
  k_scatter_add<<<TOT_K232 / 256, 256, 0, stream>>>(h2, perm2, KK2, KK1, u1);
  k_xw32<<<TOT_K132 / 256, 256, 0, stream>>>(u1, Wu0, dis1, t1);
  k_dense_apply<true><<<(BB * KK1 + 7) / 8, 256, 0, stream>>>(A1, t1, dis1, bu0, KK1, BB * KK1, hu0);
  // 8) unpool 1 + final GCN (level-0 sparse, no relu)
  k_copy<<<TOT_N32 / 256, 256, 0, stream>>>(h0, u0);
  k_scatter_add<<<TOT_K132 / 256, 256, 0, stream>>>(hu0, perm1, KK1, NN, u0);
  k_xw32<<<TOT_N32 / 256, 256, 0, stream>>>(u0, Wu1, dis0, dxw);
  k_spmm<false><<<BB * NN / 8, 256, 0, stream>>>(dxw, dis0, ncnt, nbr, bu1, hfin);
  // 9) batchnorm + MLP head
  k_bnstats<<<32, 256, 0, stream>>>(hfin, bmean, bvar);
  k_mlp<<<BB * NN / 256, 256, 0, stream>>>(hfin, bmean, bvar, gamma, beta,
                                           W1, b1, W2, b2, W3, b3, out);
}

// Round 3
// 425.506 us; speedup vs baseline: 1.4030x; 1.2250x over previous
//
#include <hip/hip_runtime.h>
#include <cmath>

#define BB 16
#define NN 1024
#define KK1 205
#define KK2 42
#define CAP 96

// ---------------- single pass over adj: degree, bitmask, neighbor lists ----
__global__ void k_deg_csr(const float* __restrict__ adj, float* __restrict__ dis0,
                          int* __restrict__ ncnt, int* __restrict__ nbr,
                          unsigned long long* __restrict__ mask) {
  int row = blockIdx.x * 4 + (threadIdx.x >> 6);   // one wave per row
  int lane = threadIdx.x & 63;
  const float* ar = adj + (size_t)row * NN;
  int base = 0;
  for (int c = 0; c < 16; ++c) {
    float v = ar[c * 64 + lane];
    unsigned long long m = __ballot(v != 0.0f);
    if (lane == c) mask[(size_t)row * 16 + c] = m;
    if (v != 0.0f) {
      int pos = base + __popcll(m & ((1ull << lane) - 1ull));
      if (pos < CAP) nbr[(size_t)row * CAP + pos] = c * 64 + lane;
    }
    base += __popcll(m);
  }
  if (lane == 0) {
    ncnt[row] = base < CAP ? base : CAP;
    dis0[row] = rsqrtf((float)base + 2.0f);
  }
}

// ---------------- dxw = dis * (x @ Wd0), IN_DIM=3 ---------------------------
__global__ void k_xw3(const float* __restrict__ x, const float* __restrict__ W,
                      const float* __restrict__ dis, float* __restrict__ out) {
  int idx = blockIdx.x * 256 + threadIdx.x;       // BB*NN*32
  int f = idx & 31; int node = idx >> 5;
  const float* xr = x + (size_t)node * 3;
  float s = xr[0] * W[f] + xr[1] * W[32 + f] + xr[2] * W[64 + f];
  out[idx] = s * dis[node];
}

// ---------------- t = dis * (in @ W), 32x32 --------------------------------
__global__ void k_xw32(const float* __restrict__ in, const float* __restrict__ W,
                       const float* __restrict__ dis, float* __restrict__ out) {
  int idx = blockIdx.x * 256 + threadIdx.x;
  int f = idx & 31; int node = idx >> 5;
  const float* xr = in + (size_t)node * 32;
  float s = 0.f;
#pragma unroll
  for (int k = 0; k < 32; ++k) s += xr[k] * W[k * 32 + f];
  out[idx] = s * dis[node];
}

// ---------------- sparse GCN apply (binary adjacency) ----------------------
template<bool RELU>
__global__ void k_spmm(const float* __restrict__ dxw, const float* __restrict__ dis,
                       const int* __restrict__ ncnt, const int* __restrict__ nbr,
                       const float* __restrict__ bias, float* __restrict__ out) {
  int tid = threadIdx.x;
  int g = tid >> 5, f = tid & 31;
  int node = blockIdx.x * 8 + g;                  // node = b*NN + i
  int b = node >> 10;
  int cnt = ncnt[node];
  const int* lst = nbr + (size_t)node * CAP;
  float acc = 0.f;
  for (int k = 0; k < cnt; ++k) {
    int j = lst[k];
    acc += dxw[(size_t)((b << 10) + j) * 32 + f];
  }
  acc += 2.0f * dxw[(size_t)node * 32 + f];
  float r = dis[node] * acc + bias[f];
  if (RELU) r = fmaxf(r, 0.f);
  out[(size_t)node * 32 + f] = r;
}

// ---------------- top-k via packed u64-key bitonic sort --------------------
// key = (~ord(v) << 32) | idx, ascending  ==> value desc, index asc on ties.
template<int MPAD>
__global__ void k_topk(const float* __restrict__ h, const float* __restrict__ p,
                       int M, int K, int* __restrict__ perm, float* __restrict__ vals) {
  __shared__ unsigned long long skey[MPAD];
  int b = blockIdx.x, t = threadIdx.x;
  float nn = 0.f;
#pragma unroll
  for (int k = 0; k < 32; ++k) nn += p[k] * p[k];
  unsigned int ordv;
  if (t < M) {
    const float* hr = h + (size_t)(b * M + t) * 32;
    float d = 0.f;
#pragma unroll
    for (int k = 0; k < 32; ++k) d += hr[k] * p[k];
    float v = tanhf(d / sqrtf(nn));
    unsigned int u = __float_as_uint(v);
    if (u == 0x80000000u) u = 0u;                 // normalize -0.0
    ordv = (u & 0x80000000u) ? ~u : (u | 0x80000000u);
  } else {
    ordv = 0u;                                     // -inf => ~ord = max => last
  }
  skey[t] = ((unsigned long long)(~ordv) << 32) | (unsigned int)t;
  __syncthreads();
  for (int k = 2; k <= MPAD; k <<= 1) {
    for (int j = k >> 1; j > 0; j >>= 1) {
      int ixj = t ^ j;
      if (ixj > t) {
        unsigned long long a = skey[t], c = skey[ixj];
        bool up = ((t & k) == 0);
        if (up == (a > c)) { skey[t] = c; skey[ixj] = a; }
      }
      __syncthreads();
    }
  }
  if (t < K) {
    unsigned long long kk = skey[t];
    unsigned int ord = ~(unsigned int)(kk >> 32);
    unsigned int u = (ord & 0x80000000u) ? (ord & 0x7FFFFFFFu) : ~ord;
    perm[b * K + t] = (int)(kk & 0xFFFFFFFFull);
    vals[b * K + t] = __uint_as_float(u);
  }
}

// ---------------- pooled gather: hp = h[perm] * vals -----------------------
__global__ void k_gather(const float* __restrict__ h, const int* __restrict__ perm,
                         const float* __restrict__ vals, int M, int K,
                         float* __restrict__ hp) {
  int idx = blockIdx.x * 256 + threadIdx.x;       // BB*K*32
  int f = idx & 31; int q = idx >> 5;
  int k = q % K, b = q / K;
  int src = perm[b * K + k];
  hp[idx] = h[(size_t)(b * M + src) * 32 + f] * vals[b * K + k];
}

// ---------------- A1 = augment(adj)[perm1,perm1] via bitsets ---------------
__global__ void k_buildA1(const unsigned long long* __restrict__ mask,
                          const int* __restrict__ perm1, float* __restrict__ A1,
                          float* __restrict__ dis1) {
  __shared__ unsigned long long smT[16 * KK1];   // transposed: smT[w*KK1 + j]
  __shared__ int sp[KK1];
  int blk = blockIdx.x;
  int b = blk / 52, chunk = blk - b * 52;
  int t = threadIdx.x;
  if (t < KK1) sp[t] = perm1[b * KK1 + t];
  __syncthreads();
  for (int q = t; q < KK1 * 16; q += 256) {
    int i = q >> 4, w = q & 15;
    smT[w * KK1 + i] = mask[((size_t)(b * NN + sp[i])) * 16 + w];
  }
  __syncthreads();
  int wave = t >> 6, lane = t & 63;
  int i = chunk * 4 + wave;
  if (i < KK1) {
    unsigned long long r[16];
#pragma unroll
    for (int w = 0; w < 16; ++w) r[w] = smT[w * KK1 + i];
    float rowsum = 0.f;
    for (int j = lane; j < KK1; j += 64) {
      int cnt = 0;
#pragma unroll
      for (int w = 0; w < 16; ++w) cnt += __popcll(r[w] & smT[w * KK1 + j]);
      int pj = sp[j];
      float edge = (float)((r[pj >> 6] >> (pj & 63)) & 1ull);
      float v = (j == i) ? 0.f : ((float)cnt + 2.f * edge);
      A1[((size_t)(b * KK1) + i) * KK1 + j] = v;
      rowsum += v;
    }
#pragma unroll
    for (int o = 32; o; o >>= 1) rowsum += __shfl_xor(rowsum, o);
    if (lane == 0) dis1[b * KK1 + i] = rsqrtf(rowsum + 2.0f);
  }
}

// ---------------- dense GCN apply (weighted A, small M) --------------------
template<bool RELU>
__global__ void k_dense_apply(const float* __restrict__ A, const float* __restrict__ t,
                              const float* __restrict__ dis, const float* __restrict__ bias,
                              int M, int rowsTotal, float* __restrict__ out) {
  int g = threadIdx.x >> 5, f = threadIdx.x & 31;
  int row = blockIdx.x * 8 + g;
  if (row >= rowsTotal) return;
  int b = row / M; int i = row - b * M;
  const float* Ar = A + (size_t)row * M;
  const float* tb = t + (size_t)b * M * 32;
  float acc = 0.f;
  for (int j = 0; j < M; ++j) acc += Ar[j] * tb[j * 32 + f];
  acc += 2.0f * tb[i * 32 + f];
  float r = dis[row] * acc + bias[f];
  if (RELU) r = fmaxf(r, 0.f);
  out[(size_t)row * 32 + f] = r;
}

// ---------------- A2 = augment(A1)[perm2,perm2] + fused dis2 ---------------
__global__ void k_buildA2(const float* __restrict__ A1, const int* __restrict__ perm2,
                          float* __restrict__ A2, float* __restrict__ dis2) {
  __shared__ float gsum[8];
  int row = blockIdx.x;                            // b*KK2 + i
  int b = row / KK2, i = row - b * KK2;
  int g = threadIdx.x >> 5, lane = threadIdx.x & 31;
  int pi = perm2[b * KK2 + i];
  const float* Ri = A1 + ((size_t)(b * KK1 + pi)) * KK1;
  float part = 0.f;
  for (int j = g; j < KK2; j += 8) {
    int pj = perm2[b * KK2 + j];
    const float* Rj = A1 + ((size_t)(b * KK1 + pj)) * KK1;
    float s = 0.f;
    for (int k = lane; k < KK1; k += 32) s += Ri[k] * Rj[k];
#pragma unroll
    for (int o = 16; o; o >>= 1) s += __shfl_xor(s, o, 32);
    float v = (i == j) ? 0.f : (s + 2.0f * Ri[pj]);
    if (lane == 0) {
      A2[((size_t)(b * KK2) + i) * KK2 + j] = v;
      part += v;
    }
  }
  if (lane == 0) gsum[g] = part;
  __syncthreads();
  if (threadIdx.x == 0) {
    float s = 0.f;
#pragma unroll
    for (int q = 0; q < 8; ++q) s += gsum[q];
    dis2[row] = rsqrtf(s + 2.0f);
  }
}

// ---------------- copy & scatter-add ---------------------------------------
__global__ void k_copy(const float* __restrict__ in, float* __restrict__ out) {
  int idx = blockIdx.x * 256 + threadIdx.x;
  out[idx] = in[idx];
}
__global__ void k_scatter_add(const float* __restrict__ src, const int* __restrict__ perm,
                              int K, int Mdst, float* __restrict__ dst) {
  int idx = blockIdx.x * 256 + threadIdx.x;       // BB*K*32
  int f = idx & 31; int q = idx >> 5;
  int k = q % K, b = q / K;
  int d = perm[b * K + k];
  dst[((size_t)(b * Mdst) + d) * 32 + f] += src[idx];
}

// ---------------- batchnorm partial stats (coalesced, atomic accumulate) ---
// grid: 128 blocks x 256 threads; block covers 128 rows; acc[0..31]=sum, [32..63]=sumsq
__global__ void k_bnstats(const float* __restrict__ h, float* __restrict__ acc) {
  int t = threadIdx.x;
  int f = t & 31, g = t >> 5;                      // 8 row-groups
  int rowBase = blockIdx.x * 128;
  float s = 0.f, sq = 0.f;
  for (int r = g; r < 128; r += 8) {
    float v = h[(size_t)(rowBase + r) * 32 + f];
    s += v; sq += v * v;
  }
  __shared__ float ls[8][32], lq[8][32];
  ls[g][f] = s; lq[g][f] = sq;
  __syncthreads();
  if (t < 32) {
    float S = 0.f, Q = 0.f;
#pragma unroll
    for (int i = 0; i < 8; ++i) { S += ls[i][t]; Q += lq[i][t]; }
    atomicAdd(&acc[t], S);
    atomicAdd(&acc[32 + t], Q);
  }
}

// ---------------- BN + 3-layer MLP head (LDS-staged weights) ---------------
// grid: 256 blocks x 64 threads; thread = node.
__global__ __launch_bounds__(64) void k_mlp(
    const float* __restrict__ h, const float* __restrict__ acc,
    const float* __restrict__ gamma, const float* __restrict__ beta,
    const float* __restrict__ W1, const float* __restrict__ b1,
    const float* __restrict__ W2, const float* __restrict__ b2,
    const float* __restrict__ W3, const float* __restrict__ b3,
    float* __restrict__ out) {
  __shared__ float sW1[1024], sW2[1024], sW3[128];
  __shared__ float sb1[32], sb2[32], sb3[4], sscale[32], sshift[32];
  int t = threadIdx.x;
  { // coalesced float4 staging
    const float4* W1v = (const float4*)W1; float4* d1 = (float4*)sW1;
#pragma unroll
    for (int i = 0; i < 4; ++i) d1[t + i * 64] = W1v[t + i * 64];
    const float4* W2v = (const float4*)W2; float4* d2 = (float4*)sW2;
#pragma unroll
    for (int i = 0; i < 4; ++i) d2[t + i * 64] = W2v[t + i * 64];
    if (t < 32) ((float4*)sW3)[t] = ((const float4*)W3)[t];
    if (t < 32) { sb1[t] = b1[t]; sb2[t] = b2[t]; }
    if (t < 4) sb3[t] = b3[t];
    if (t < 32) {
      const float inv = 1.0f / (float)(BB * NN);
      float m = acc[t] * inv;
      float v = acc[32 + t] * inv - m * m;
      float sc = gamma[t] * rsqrtf(v + 1e-5f);
      sscale[t] = sc;
      sshift[t] = beta[t] - m * sc;
    }
  }
  __syncthreads();
  int node = blockIdx.x * 64 + t;
  const float4* hr = (const float4*)(h + (size_t)node * 32);
  float hn[32];
#pragma unroll
  for (int i = 0; i < 8; ++i) {
    float4 x = hr[i];
    hn[i * 4 + 0] = x.x * sscale[i * 4 + 0] + sshift[i * 4 + 0];
    hn[i * 4 + 1] = x.y * sscale[i * 4 + 1] + sshift[i * 4 + 1];
    hn[i * 4 + 2] = x.z * sscale[i * 4 + 2] + sshift[i * 4 + 2];
    hn[i * 4 + 3] = x.w * sscale[i * 4 + 3] + sshift[i * 4 + 3];
  }
  float r1[32];
#pragma unroll
  for (int f = 0; f < 32; ++f) r1[f] = sb1[f];
#pragma unroll
  for (int k = 0; k < 32; ++k) {
    float a = hn[k];
#pragma unroll
    for (int f = 0; f < 32; ++f) r1[f] += a * sW1[k * 32 + f];
  }
#pragma unroll
  for (int f = 0; f < 32; ++f) r1[f] = r1[f] > 0.f ? r1[f] : 0.01f * r1[f];
  float r2[32];
#pragma unroll
  for (int f = 0; f < 32; ++f) r2[f] = sb2[f];
#pragma unroll
  for (int k = 0; k < 32; ++k) {
    float a = r1[k];
#pragma unroll
    for (int f = 0; f < 32; ++f) r2[f] += a * sW2[k * 32 + f];
  }
#pragma unroll
  for (int f = 0; f < 32; ++f) r2[f] = r2[f] > 0.f ? r2[f] : 0.01f * r2[f];
  float r3[4];
#pragma unroll
  for (int c = 0; c < 4; ++c) r3[c] = sb3[c];
#pragma unroll
  for (int k = 0; k < 32; ++k) {
    float a = r2[k];
#pragma unroll
    for (int c = 0; c < 4; ++c) r3[c] += a * sW3[k * 4 + c];
  }
  float4 o;
  o.x = 1.0f / (1.0f + expf(-r3[0]));
  o.y = r3[1]; o.z = r3[2]; o.w = r3[3];
  ((float4*)out)[node] = o;
}

extern "C" void kernel_launch(void* const* d_in, const int* in_sizes, int n_in,
                              void* d_out, int out_size, void* d_ws, size_t ws_size,
                              hipStream_t stream) {
  const float* x    = (const float*)d_in[0];
  const float* adj  = (const float*)d_in[1];
  const float* Wd0  = (const float*)d_in[2];
  const float* bd0  = (const float*)d_in[3];
  const float* Wd1  = (const float*)d_in[4];
  const float* bd1  = (const float*)d_in[5];
  const float* Wd2  = (const float*)d_in[6];
  const float* bd2  = (const float*)d_in[7];
  const float* Wu0  = (const float*)d_in[8];
  const float* bu0  = (const float*)d_in[9];
  const float* Wu1  = (const float*)d_in[10];
  const float* bu1  = (const float*)d_in[11];
  const float* p1   = (const float*)d_in[12];
  const float* p2   = (const float*)d_in[13];
  const float* gamma= (const float*)d_in[14];
  const float* beta = (const float*)d_in[15];
  const float* W1   = (const float*)d_in[16];
  const float* b1   = (const float*)d_in[17];
  const float* W2   = (const float*)d_in[18];
  const float* b2   = (const float*)d_in[19];
  const float* W3   = (const float*)d_in[20];
  const float* b3   = (const float*)d_in[21];
  float* out = (float*)d_out;

  char* w = (char*)d_ws;
  auto alloc = [&](size_t bytes) -> void* {
    void* p = (void*)w;
    w += (bytes + 255) & ~(size_t)255;
    return p;
  };
  float* dis0 = (float*)alloc(BB * NN * 4);
  int*   ncnt = (int*)alloc(BB * NN * 4);
  int*   nbr  = (int*)alloc((size_t)BB * NN * CAP * 4);
  unsigned long long* mask = (unsigned long long*)alloc((size_t)BB * NN * 16 * 8);
  float* dxw  = (float*)alloc((size_t)BB * NN * 32 * 4);
  float* h0   = (float*)alloc((size_t)BB * NN * 32 * 4);
  int*   perm1= (int*)alloc(BB * KK1 * 4);
  float* vals1= (float*)alloc(BB * KK1 * 4);
  float* hp1  = (float*)alloc((size_t)BB * KK1 * 32 * 4);
  float* A1   = (float*)alloc((size_t)BB * KK1 * KK1 * 4);
  float* dis1 = (float*)alloc(BB * KK1 * 4);
  float* t1   = (float*)alloc((size_t)BB * KK1 * 32 * 4);
  float* h1   = (float*)alloc((size_t)BB * KK1 * 32 * 4);
  int*   perm2= (int*)alloc(BB * KK2 * 4);
  float* vals2= (float*)alloc(BB * KK2 * 4);
  float* hp2  = (float*)alloc((size_t)BB * KK2 * 32 * 4);
  float* A2   = (float*)alloc((size_t)BB * KK2 * KK2 * 4);
  float* dis2 = (float*)alloc(BB * KK2 * 4);
  float* t2   = (float*)alloc((size_t)BB * KK2 * 32 * 4);
  float* h2   = (float*)alloc((size_t)BB * KK2 * 32 * 4);
  float* u1   = (float*)alloc((size_t)BB * KK1 * 32 * 4);
  float* hu0  = (float*)alloc((size_t)BB * KK1 * 32 * 4);
  float* u0   = (float*)alloc((size_t)BB * NN * 32 * 4);
  float* hfin = (float*)alloc((size_t)BB * NN * 32 * 4);
  float* bnacc= (float*)alloc(64 * 4);

  const int TOT_N32  = BB * NN * 32;     // 524288
  const int TOT_K132 = BB * KK1 * 32;    // 104960
  const int TOT_K232 = BB * KK2 * 32;    // 21504

  // 1) single adj pass: degree + bitmask + CSR
  k_deg_csr<<<BB * NN / 4, 256, 0, stream>>>(adj, dis0, ncnt, nbr, mask);
  // 2) GCN0
  k_xw3<<<TOT_N32 / 256, 256, 0, stream>>>(x, Wd0, dis0, dxw);
  k_spmm<true><<<BB * NN / 8, 256, 0, stream>>>(dxw, dis0, ncnt, nbr, bd0, h0);
  // 3) top-k pool 1
  k_topk<1024><<<BB, 1024, 0, stream>>>(h0, p1, NN, KK1, perm1, vals1);
  k_gather<<<TOT_K132 / 256, 256, 0, stream>>>(h0, perm1, vals1, NN, KK1, hp1);
  k_buildA1<<<BB * 52, 256, 0, stream>>>(mask, perm1, A1, dis1);
  // 4) GCN1
  k_xw32<<<TOT_K132 / 256, 256, 0, stream>>>(hp1, Wd1, dis1, t1);
  k_dense_apply<true><<<(BB * KK1 + 7) / 8, 256, 0, stream>>>(A1, t1, dis1, bd1, KK1, BB * KK1, h1);
  // 5) top-k pool 2
  k_topk<256><<<BB, 256, 0, stream>>>(h1, p2, KK1, KK2, perm2, vals2);
  k_gather<<<TOT_K232 / 256, 256, 0, stream>>>(h1, perm2, vals2, KK1, KK2, hp2);
  k_buildA2<<<BB * KK2, 256, 0, stream>>>(A1, perm2, A2, dis2);
  // 6) GCN2
  k_xw32<<<TOT_K232 / 256, 256, 0, stream>>>(hp2, Wd2, dis2, t2);
  k_dense_apply<true><<<(BB * KK2 + 7) / 8, 256, 0, stream>>>(A2, t2, dis2, bd2, KK2, BB * KK2, h2);
  // 7) unpool 2 + up-GCN (level-1)
  k_copy<<<TOT_K132 / 256, 256, 0, stream>>>(h1, u1);
  k_scatter_add<<<TOT_K232 / 256, 256, 0, stream>>>(h2, perm2, KK2, KK1, u1);
  k_xw32<<<TOT_K132 / 256, 256, 0, stream>>>(u1, Wu0, dis1, t1);
  k_dense_apply<true><<<(BB * KK1 + 7) / 8, 256, 0, stream>>>(A1, t1, dis1, bu0, KK1, BB * KK1, hu0);
  // 8) unpool 1 + final GCN (level-0 sparse, no relu)
  k_copy<<<TOT_N32 / 256, 256, 0, stream>>>(h0, u0);
  k_scatter_add<<<TOT_K132 / 256, 256, 0, stream>>>(hu0, perm1, KK1, NN, u0);
  k_xw32<<<TOT_N32 / 256, 256, 0, stream>>>(u0, Wu1, dis0, dxw);
  k_spmm<false><<<BB * NN / 8, 256, 0, stream>>>(dxw, dis0, ncnt, nbr, bu1, hfin);
  // 9) batchnorm (partial+atomic) + fused BN/MLP head
  hipMemsetAsync(bnacc, 0, 64 * sizeof(float), stream);
  k_bnstats<<<128, 256, 0, stream>>>(hfin, bnacc);
  k_mlp<<<BB * NN / 64, 64, 0, stream>>>(hfin, bnacc, gamma, beta,
                                         W1, b1, W2, b2, W3, b3, out);
}

// Round 4
// 343.078 us; speedup vs baseline: 1.7400x; 1.2403x over previous
//
#include <hip/hip_runtime.h>
#include <cmath>

#define BB 16
#define NN 1024
#define KK1 205
#define KK2 42
#define CAP 96

// ---------------- single pass over adj: degree, bitmask, neighbor lists ----
__global__ void k_deg_csr(const float* __restrict__ adj, float* __restrict__ dis0,
                          int* __restrict__ ncnt, int* __restrict__ nbr,
                          unsigned long long* __restrict__ mask) {
  int row = blockIdx.x * 4 + (threadIdx.x >> 6);   // one wave per row
  int lane = threadIdx.x & 63;
  const float* ar = adj + (size_t)row * NN;
  int base = 0;
  for (int c = 0; c < 16; ++c) {
    float v = ar[c * 64 + lane];
    unsigned long long m = __ballot(v != 0.0f);
    if (lane == c) mask[(size_t)row * 16 + c] = m;
    if (v != 0.0f) {
      int pos = base + __popcll(m & ((1ull << lane) - 1ull));
      if (pos < CAP) nbr[(size_t)row * CAP + pos] = c * 64 + lane;
    }
    base += __popcll(m);
  }
  if (lane == 0) {
    ncnt[row] = base < CAP ? base : CAP;
    dis0[row] = rsqrtf((float)base + 2.0f);
  }
}

// ---------------- dxw = dis * (x @ Wd0), IN_DIM=3 ---------------------------
__global__ void k_xw3(const float* __restrict__ x, const float* __restrict__ W,
                      const float* __restrict__ dis, float* __restrict__ out) {
  int idx = blockIdx.x * 256 + threadIdx.x;       // BB*NN*32
  int f = idx & 31; int node = idx >> 5;
  const float* xr = x + (size_t)node * 3;
  float s = xr[0] * W[f] + xr[1] * W[32 + f] + xr[2] * W[64 + f];
  out[idx] = s * dis[node];
}

// ---------------- t = dis * (in @ W), 32x32 --------------------------------
__global__ void k_xw32(const float* __restrict__ in, const float* __restrict__ W,
                       const float* __restrict__ dis, float* __restrict__ out) {
  int idx = blockIdx.x * 256 + threadIdx.x;
  int f = idx & 31; int node = idx >> 5;
  const float* xr = in + (size_t)node * 32;
  float s = 0.f;
#pragma unroll
  for (int k = 0; k < 32; ++k) s += xr[k] * W[k * 32 + f];
  out[idx] = s * dis[node];
}

// ---------------- sparse GCN apply (binary adjacency) ----------------------
template<bool RELU>
__global__ void k_spmm(const float* __restrict__ dxw, const float* __restrict__ dis,
                       const int* __restrict__ ncnt, const int* __restrict__ nbr,
                       const float* __restrict__ bias, float* __restrict__ out) {
  int tid = threadIdx.x;
  int g = tid >> 5, f = tid & 31;
  int node = blockIdx.x * 8 + g;                  // node = b*NN + i
  int b = node >> 10;
  int cnt = ncnt[node];
  const int* lst = nbr + (size_t)node * CAP;
  float acc = 0.f;
  for (int k = 0; k < cnt; ++k) {
    int j = lst[k];
    acc += dxw[(size_t)((b << 10) + j) * 32 + f];
  }
  acc += 2.0f * dxw[(size_t)node * 32 + f];
  float r = dis[node] * acc + bias[f];
  if (RELU) r = fmaxf(r, 0.f);
  out[(size_t)node * 32 + f] = r;
}

// ---------------- top-k via packed u64-key bitonic sort --------------------
// key = (~ord(v) << 32) | idx, ascending  ==> value desc, index asc on ties.
template<int MPAD>
__global__ void k_topk(const float* __restrict__ h, const float* __restrict__ p,
                       int M, int K, int* __restrict__ perm, float* __restrict__ vals) {
  __shared__ unsigned long long skey[MPAD];
  int b = blockIdx.x, t = threadIdx.x;
  float nn = 0.f;
#pragma unroll
  for (int k = 0; k < 32; ++k) nn += p[k] * p[k];
  unsigned int ordv;
  if (t < M) {
    const float* hr = h + (size_t)(b * M + t) * 32;
    float d = 0.f;
#pragma unroll
    for (int k = 0; k < 32; ++k) d += hr[k] * p[k];
    float v = tanhf(d / sqrtf(nn));
    unsigned int u = __float_as_uint(v);
    if (u == 0x80000000u) u = 0u;                 // normalize -0.0
    ordv = (u & 0x80000000u) ? ~u : (u | 0x80000000u);
  } else {
    ordv = 0u;                                     // -inf => ~ord = max => last
  }
  skey[t] = ((unsigned long long)(~ordv) << 32) | (unsigned int)t;
  __syncthreads();
  for (int k = 2; k <= MPAD; k <<= 1) {
    for (int j = k >> 1; j > 0; j >>= 1) {
      int ixj = t ^ j;
      if (ixj > t) {
        unsigned long long a = skey[t], c = skey[ixj];
        bool up = ((t & k) == 0);
        if (up == (a > c)) { skey[t] = c; skey[ixj] = a; }
      }
      __syncthreads();
    }
  }
  if (t < K) {
    unsigned long long kk = skey[t];
    unsigned int ord = ~(unsigned int)(kk >> 32);
    unsigned int u = (ord & 0x80000000u) ? (ord & 0x7FFFFFFFu) : ~ord;
    perm[b * K + t] = (int)(kk & 0xFFFFFFFFull);
    vals[b * K + t] = __uint_as_float(u);
  }
}

// ---------------- pooled gather: hp = h[perm] * vals -----------------------
__global__ void k_gather(const float* __restrict__ h, const int* __restrict__ perm,
                         const float* __restrict__ vals, int M, int K,
                         float* __restrict__ hp) {
  int idx = blockIdx.x * 256 + threadIdx.x;       // BB*K*32
  int f = idx & 31; int q = idx >> 5;
  int k = q % K, b = q / K;
  int src = perm[b * K + k];
  hp[idx] = h[(size_t)(b * M + src) * 32 + f] * vals[b * K + k];
}

// ---------------- A1 = augment(adj)[perm1,perm1] via bitsets ---------------
__global__ void k_buildA1(const unsigned long long* __restrict__ mask,
                          const int* __restrict__ perm1, float* __restrict__ A1,
                          float* __restrict__ dis1) {
  __shared__ unsigned long long smT[16 * KK1];   // transposed: smT[w*KK1 + j]
  __shared__ int sp[KK1];
  int blk = blockIdx.x;
  int b = blk / 52, chunk = blk - b * 52;
  int t = threadIdx.x;
  if (t < KK1) sp[t] = perm1[b * KK1 + t];
  __syncthreads();
  for (int q = t; q < KK1 * 16; q += 256) {
    int i = q >> 4, w = q & 15;
    smT[w * KK1 + i] = mask[((size_t)(b * NN + sp[i])) * 16 + w];
  }
  __syncthreads();
  int wave = t >> 6, lane = t & 63;
  int i = chunk * 4 + wave;
  if (i < KK1) {
    unsigned long long r[16];
#pragma unroll
    for (int w = 0; w < 16; ++w) r[w] = smT[w * KK1 + i];
    float rowsum = 0.f;
    for (int j = lane; j < KK1; j += 64) {
      int cnt = 0;
#pragma unroll
      for (int w = 0; w < 16; ++w) cnt += __popcll(r[w] & smT[w * KK1 + j]);
      int pj = sp[j];
      float edge = (float)((r[pj >> 6] >> (pj & 63)) & 1ull);
      float v = (j == i) ? 0.f : ((float)cnt + 2.f * edge);
      A1[((size_t)(b * KK1) + i) * KK1 + j] = v;
      rowsum += v;
    }
#pragma unroll
    for (int o = 32; o; o >>= 1) rowsum += __shfl_xor(rowsum, o);
    if (lane == 0) dis1[b * KK1 + i] = rsqrtf(rowsum + 2.0f);
  }
}

// ---------------- dense GCN apply: one block per row, 8-way K split --------
template<bool RELU>
__global__ __launch_bounds__(256) void k_dense_apply(
    const float* __restrict__ A, const float* __restrict__ t,
    const float* __restrict__ dis, const float* __restrict__ bias,
    int M, float* __restrict__ out) {
  int row = blockIdx.x;
  int b = row / M, i = row - b * M;
  int tid = threadIdx.x;
  int g = tid >> 5, f = tid & 31;
  const float* Ar = A + (size_t)row * M;
  const float* tb = t + (size_t)b * M * 32;
  float acc = 0.f;
  for (int j = g; j < M; j += 8)
    acc += Ar[j] * tb[j * 32 + f];
  __shared__ float ls[8][32];
  ls[g][f] = acc;
  __syncthreads();
  if (tid < 32) {
    float s = 0.f;
#pragma unroll
    for (int q = 0; q < 8; ++q) s += ls[q][tid];
    s += 2.0f * tb[i * 32 + tid];
    float r = dis[row] * s + bias[tid];
    if (RELU) r = fmaxf(r, 0.f);
    out[(size_t)row * 32 + tid] = r;
  }
}

// ---------------- A2 = augment(A1)[perm2,perm2] + fused dis2 ---------------
__global__ void k_buildA2(const float* __restrict__ A1, const int* __restrict__ perm2,
                          float* __restrict__ A2, float* __restrict__ dis2) {
  __shared__ float gsum[8];
  int row = blockIdx.x;                            // b*KK2 + i
  int b = row / KK2, i = row - b * KK2;
  int g = threadIdx.x >> 5, lane = threadIdx.x & 31;
  int pi = perm2[b * KK2 + i];
  const float* Ri = A1 + ((size_t)(b * KK1 + pi)) * KK1;
  float part = 0.f;
  for (int j = g; j < KK2; j += 8) {
    int pj = perm2[b * KK2 + j];
    const float* Rj = A1 + ((size_t)(b * KK1 + pj)) * KK1;
    float s = 0.f;
    for (int k = lane; k < KK1; k += 32) s += Ri[k] * Rj[k];
#pragma unroll
    for (int o = 16; o; o >>= 1) s += __shfl_xor(s, o, 32);
    float v = (i == j) ? 0.f : (s + 2.0f * Ri[pj]);
    if (lane == 0) {
      A2[((size_t)(b * KK2) + i) * KK2 + j] = v;
      part += v;
    }
  }
  if (lane == 0) gsum[g] = part;
  __syncthreads();
  if (threadIdx.x == 0) {
    float s = 0.f;
#pragma unroll
    for (int q = 0; q < 8; ++q) s += gsum[q];
    dis2[row] = rsqrtf(s + 2.0f);
  }
}

// ---------------- copy & scatter-add ---------------------------------------
__global__ void k_copy(const float* __restrict__ in, float* __restrict__ out) {
  int idx = blockIdx.x * 256 + threadIdx.x;
  out[idx] = in[idx];
}
__global__ void k_scatter_add(const float* __restrict__ src, const int* __restrict__ perm,
                              int K, int Mdst, float* __restrict__ dst) {
  int idx = blockIdx.x * 256 + threadIdx.x;       // BB*K*32
  int f = idx & 31; int q = idx >> 5;
  int k = q % K, b = q / K;
  int d = perm[b * K + k];
  dst[((size_t)(b * Mdst) + d) * 32 + f] += src[idx];
}

// ---------------- batchnorm partial stats (coalesced, atomic accumulate) ---
__global__ void k_bnstats(const float* __restrict__ h, float* __restrict__ acc) {
  int t = threadIdx.x;
  int f = t & 31, g = t >> 5;                      // 8 row-groups
  int rowBase = blockIdx.x * 128;
  float s = 0.f, sq = 0.f;
  for (int r = g; r < 128; r += 8) {
    float v = h[(size_t)(rowBase + r) * 32 + f];
    s += v; sq += v * v;
  }
  __shared__ float ls[8][32], lq[8][32];
  ls[g][f] = s; lq[g][f] = sq;
  __syncthreads();
  if (t < 32) {
    float S = 0.f, Q = 0.f;
#pragma unroll
    for (int i = 0; i < 8; ++i) { S += ls[i][t]; Q += lq[i][t]; }
    atomicAdd(&acc[t], S);
    atomicAdd(&acc[32 + t], Q);
  }
}

// ---------------- BN + 3-layer MLP head (LDS-staged weights) ---------------
__global__ __launch_bounds__(64) void k_mlp(
    const float* __restrict__ h, const float* __restrict__ acc,
    const float* __restrict__ gamma, const float* __restrict__ beta,
    const float* __restrict__ W1, const float* __restrict__ b1,
    const float* __restrict__ W2, const float* __restrict__ b2,
    const float* __restrict__ W3, const float* __restrict__ b3,
    float* __restrict__ out) {
  __shared__ float sW1[1024], sW2[1024], sW3[128];
  __shared__ float sb1[32], sb2[32], sb3[4], sscale[32], sshift[32];
  int t = threadIdx.x;
  {
    const float4* W1v = (const float4*)W1; float4* d1 = (float4*)sW1;
#pragma unroll
    for (int i = 0; i < 4; ++i) d1[t + i * 64] = W1v[t + i * 64];
    const float4* W2v = (const float4*)W2; float4* d2 = (float4*)sW2;
#pragma unroll
    for (int i = 0; i < 4; ++i) d2[t + i * 64] = W2v[t + i * 64];
    if (t < 32) ((float4*)sW3)[t] = ((const float4*)W3)[t];
    if (t < 32) { sb1[t] = b1[t]; sb2[t] = b2[t]; }
    if (t < 4) sb3[t] = b3[t];
    if (t < 32) {
      const float inv = 1.0f / (float)(BB * NN);
      float m = acc[t] * inv;
      float v = acc[32 + t] * inv - m * m;
      float sc = gamma[t] * rsqrtf(v + 1e-5f);
      sscale[t] = sc;
      sshift[t] = beta[t] - m * sc;
    }
  }
  __syncthreads();
  int node = blockIdx.x * 64 + t;
  const float4* hr = (const float4*)(h + (size_t)node * 32);
  float hn[32];
#pragma unroll
  for (int i = 0; i < 8; ++i) {
    float4 x = hr[i];
    hn[i * 4 + 0] = x.x * sscale[i * 4 + 0] + sshift[i * 4 + 0];
    hn[i * 4 + 1] = x.y * sscale[i * 4 + 1] + sshift[i * 4 + 1];
    hn[i * 4 + 2] = x.z * sscale[i * 4 + 2] + sshift[i * 4 + 2];
    hn[i * 4 + 3] = x.w * sscale[i * 4 + 3] + sshift[i * 4 + 3];
  }
  float r1[32];
#pragma unroll
  for (int f = 0; f < 32; ++f) r1[f] = sb1[f];
#pragma unroll
  for (int k = 0; k < 32; ++k) {
    float a = hn[k];
#pragma unroll
    for (int f = 0; f < 32; ++f) r1[f] += a * sW1[k * 32 + f];
  }
#pragma unroll
  for (int f = 0; f < 32; ++f) r1[f] = r1[f] > 0.f ? r1[f] : 0.01f * r1[f];
  float r2[32];
#pragma unroll
  for (int f = 0; f < 32; ++f) r2[f] = sb2[f];
#pragma unroll
  for (int k = 0; k < 32; ++k) {
    float a = r1[k];
#pragma unroll
    for (int f = 0; f < 32; ++f) r2[f] += a * sW2[k * 32 + f];
  }
#pragma unroll
  for (int f = 0; f < 32; ++f) r2[f] = r2[f] > 0.f ? r2[f] : 0.01f * r2[f];
  float r3[4];
#pragma unroll
  for (int c = 0; c < 4; ++c) r3[c] = sb3[c];
#pragma unroll
  for (int k = 0; k < 32; ++k) {
    float a = r2[k];
#pragma unroll
    for (int c = 0; c < 4; ++c) r3[c] += a * sW3[k * 4 + c];
  }
  float4 o;
  o.x = 1.0f / (1.0f + expf(-r3[0]));
  o.y = r3[1]; o.z = r3[2]; o.w = r3[3];
  ((float4*)out)[node] = o;
}

extern "C" void kernel_launch(void* const* d_in, const int* in_sizes, int n_in,
                              void* d_out, int out_size, void* d_ws, size_t ws_size,
                              hipStream_t stream) {
  const float* x    = (const float*)d_in[0];
  const float* adj  = (const float*)d_in[1];
  const float* Wd0  = (const float*)d_in[2];
  const float* bd0  = (const float*)d_in[3];
  const float* Wd1  = (const float*)d_in[4];
  const float* bd1  = (const float*)d_in[5];
  const float* Wd2  = (const float*)d_in[6];
  const float* bd2  = (const float*)d_in[7];
  const float* Wu0  = (const float*)d_in[8];
  const float* bu0  = (const float*)d_in[9];
  const float* Wu1  = (const float*)d_in[10];
  const float* bu1  = (const float*)d_in[11];
  const float* p1   = (const float*)d_in[12];
  const float* p2   = (const float*)d_in[13];
  const float* gamma= (const float*)d_in[14];
  const float* beta = (const float*)d_in[15];
  const float* W1   = (const float*)d_in[16];
  const float* b1   = (const float*)d_in[17];
  const float* W2   = (const float*)d_in[18];
  const float* b2   = (const float*)d_in[19];
  const float* W3   = (const float*)d_in[20];
  const float* b3   = (const float*)d_in[21];
  float* out = (float*)d_out;

  char* w = (char*)d_ws;
  auto alloc = [&](size_t bytes) -> void* {
    void* p = (void*)w;
    w += (bytes + 255) & ~(size_t)255;
    return p;
  };
  float* dis0 = (float*)alloc(BB * NN * 4);
  int*   ncnt = (int*)alloc(BB * NN * 4);
  int*   nbr  = (int*)alloc((size_t)BB * NN * CAP * 4);
  unsigned long long* mask = (unsigned long long*)alloc((size_t)BB * NN * 16 * 8);
  float* dxw  = (float*)alloc((size_t)BB * NN * 32 * 4);
  float* h0   = (float*)alloc((size_t)BB * NN * 32 * 4);
  int*   perm1= (int*)alloc(BB * KK1 * 4);
  float* vals1= (float*)alloc(BB * KK1 * 4);
  float* hp1  = (float*)alloc((size_t)BB * KK1 * 32 * 4);
  float* A1   = (float*)alloc((size_t)BB * KK1 * KK1 * 4);
  float* dis1 = (float*)alloc(BB * KK1 * 4);
  float* t1   = (float*)alloc((size_t)BB * KK1 * 32 * 4);
  float* h1   = (float*)alloc((size_t)BB * KK1 * 32 * 4);
  int*   perm2= (int*)alloc(BB * KK2 * 4);
  float* vals2= (float*)alloc(BB * KK2 * 4);
  float* hp2  = (float*)alloc((size_t)BB * KK2 * 32 * 4);
  float* A2   = (float*)alloc((size_t)BB * KK2 * KK2 * 4);
  float* dis2 = (float*)alloc(BB * KK2 * 4);
  float* t2   = (float*)alloc((size_t)BB * KK2 * 32 * 4);
  float* h2   = (float*)alloc((size_t)BB * KK2 * 32 * 4);
  float* u1   = (float*)alloc((size_t)BB * KK1 * 32 * 4);
  float* hu0  = (float*)alloc((size_t)BB * KK1 * 32 * 4);
  float* u0   = (float*)alloc((size_t)BB * NN * 32 * 4);
  float* hfin = (float*)alloc((size_t)BB * NN * 32 * 4);
  float* bnacc= (float*)alloc(64 * 4);

  const int TOT_N32  = BB * NN * 32;     // 524288
  const int TOT_K132 = BB * KK1 * 32;    // 104960
  const int TOT_K232 = BB * KK2 * 32;    // 21504

  // 1) single adj pass: degree + bitmask + CSR
  k_deg_csr<<<BB * NN / 4, 256, 0, stream>>>(adj, dis0, ncnt, nbr, mask);
  // 2) GCN0
  k_xw3<<<TOT_N32 / 256, 256, 0, stream>>>(x, Wd0, dis0, dxw);
  k_spmm<true><<<BB * NN / 8, 256, 0, stream>>>(dxw, dis0, ncnt, nbr, bd0, h0);
  // 3) top-k pool 1
  k_topk<1024><<<BB, 1024, 0, stream>>>(h0, p1, NN, KK1, perm1, vals1);
  k_gather<<<TOT_K132 / 256, 256, 0, stream>>>(h0, perm1, vals1, NN, KK1, hp1);
  k_buildA1<<<BB * 52, 256, 0, stream>>>(mask, perm1, A1, dis1);
  // 4) GCN1
  k_xw32<<<TOT_K132 / 256, 256, 0, stream>>>(hp1, Wd1, dis1, t1);
  k_dense_apply<true><<<BB * KK1, 256, 0, stream>>>(A1, t1, dis1, bd1, KK1, h1);
  // 5) top-k pool 2
  k_topk<256><<<BB, 256, 0, stream>>>(h1, p2, KK1, KK2, perm2, vals2);
  k_gather<<<TOT_K232 / 256, 256, 0, stream>>>(h1, perm2, vals2, KK1, KK2, hp2);
  k_buildA2<<<BB * KK2, 256, 0, stream>>>(A1, perm2, A2, dis2);
  // 6) GCN2
  k_xw32<<<TOT_K232 / 256, 256, 0, stream>>>(hp2, Wd2, dis2, t2);
  k_dense_apply<true><<<BB * KK2, 256, 0, stream>>>(A2, t2, dis2, bd2, KK2, h2);
  // 7) unpool 2 + up-GCN (level-1)
  k_copy<<<TOT_K132 / 256, 256, 0, stream>>>(h1, u1);
  k_scatter_add<<<TOT_K232 / 256, 256, 0, stream>>>(h2, perm2, KK2, KK1, u1);
  k_xw32<<<TOT_K132 / 256, 256, 0, stream>>>(u1, Wu0, dis1, t1);
  k_dense_apply<true><<<BB * KK1, 256, 0, stream>>>(A1, t1, dis1, bu0, KK1, hu0);
  // 8) unpool 1 + final GCN (level-0 sparse, no relu)
  k_copy<<<TOT_N32 / 256, 256, 0, stream>>>(h0, u0);
  k_scatter_add<<<TOT_K132 / 256, 256, 0, stream>>>(hu0, perm1, KK1, NN, u0);
  k_xw32<<<TOT_N32 / 256, 256, 0, stream>>>(u0, Wu1, dis0, dxw);
  k_spmm<false><<<BB * NN / 8, 256, 0, stream>>>(dxw, dis0, ncnt, nbr, bu1, hfin);
  // 9) batchnorm (partial+atomic) + fused BN/MLP head
  hipMemsetAsync(bnacc, 0, 64 * sizeof(float), stream);
  k_bnstats<<<128, 256, 0, stream>>>(hfin, bnacc);
  k_mlp<<<BB * NN / 64, 64, 0, stream>>>(hfin, bnacc, gamma, beta,
                                         W1, b1, W2, b2, W3, b3, out);
}

// Round 5
// 304.294 us; speedup vs baseline: 1.9618x; 1.1275x over previous
//
#include <hip/hip_runtime.h>
#include <cmath>

#define BB 16
#define NN 1024
#define KK1 205
#define KK2 42
#define CAP 96

// ------- single adj pass: degree, bitmask, neighbor list, fused x@Wd0 ------
__global__ void k_deg_csr(const float* __restrict__ adj, const float* __restrict__ x,
                          const float* __restrict__ W,
                          float* __restrict__ dis0, int* __restrict__ ncnt,
                          int* __restrict__ nbr, unsigned long long* __restrict__ mask,
                          float* __restrict__ dxw) {
  int row = blockIdx.x * 4 + (threadIdx.x >> 6);   // one wave per row
  int lane = threadIdx.x & 63;
  const float* ar = adj + (size_t)row * NN;
  int base = 0;
  for (int c = 0; c < 16; ++c) {
    float v = ar[c * 64 + lane];
    unsigned long long m = __ballot(v != 0.0f);
    if (lane == c) mask[(size_t)row * 16 + c] = m;
    if (v != 0.0f) {
      int pos = base + __popcll(m & ((1ull << lane) - 1ull));
      if (pos < CAP) nbr[(size_t)row * CAP + pos] = c * 64 + lane;
    }
    base += __popcll(m);
  }
  float dis = rsqrtf((float)base + 2.0f);
  if (lane == 0) {
    ncnt[row] = base < CAP ? base : CAP;
    dis0[row] = dis;
  }
  if (lane < 32) {                                  // fused dxw = dis*(x@Wd0)
    float x0 = x[row * 3], x1 = x[row * 3 + 1], x2 = x[row * 3 + 2];
    float s = x0 * W[lane] + x1 * W[32 + lane] + x2 * W[64 + lane];
    dxw[(size_t)row * 32 + lane] = s * dis;
  }
}

// ---------------- sparse GCN apply (binary adjacency), x4 unrolled ---------
template<bool RELU>
__global__ void k_spmm(const float* __restrict__ dxw, const float* __restrict__ dis,
                       const int* __restrict__ ncnt, const int* __restrict__ nbr,
                       const float* __restrict__ bias, float* __restrict__ out) {
  int tid = threadIdx.x;
  int g = tid >> 5, f = tid & 31;
  int node = blockIdx.x * 8 + g;                  // node = b*NN + i
  int b = node >> 10;
  int cnt = ncnt[node];
  const int* lst = nbr + (size_t)node * CAP;      // 384B-aligned rows
  const float* dbase = dxw + ((size_t)(b << 10) << 5);
  float a0 = 0.f, a1 = 0.f, a2 = 0.f, a3 = 0.f;
  int k = 0;
  for (; k + 4 <= cnt; k += 4) {
    int4 j4 = *(const int4*)(lst + k);
    a0 += dbase[(size_t)j4.x * 32 + f];
    a1 += dbase[(size_t)j4.y * 32 + f];
    a2 += dbase[(size_t)j4.z * 32 + f];
    a3 += dbase[(size_t)j4.w * 32 + f];
  }
  for (; k < cnt; ++k) a0 += dbase[(size_t)lst[k] * 32 + f];
  float acc = (a0 + a1) + (a2 + a3);
  acc += 2.0f * dxw[(size_t)node * 32 + f];
  float r = dis[node] * acc + bias[f];
  if (RELU) r = fmaxf(r, 0.f);
  out[(size_t)node * 32 + f] = r;
}

// ---------------- top-k via packed u64-key bitonic sort + inverse map ------
// key = (~ord(v) << 32) | idx, ascending  ==> value desc, index asc on ties.
template<int MPAD>
__global__ void k_topk(const float* __restrict__ h, const float* __restrict__ p,
                       int M, int K, int* __restrict__ perm, float* __restrict__ vals,
                       int* __restrict__ inv) {
  __shared__ unsigned long long skey[MPAD];
  int b = blockIdx.x, t = threadIdx.x;
  float nn = 0.f;
#pragma unroll
  for (int k = 0; k < 32; ++k) nn += p[k] * p[k];
  unsigned int ordv;
  if (t < M) {
    const float* hr = h + (size_t)(b * M + t) * 32;
    float d = 0.f;
#pragma unroll
    for (int k = 0; k < 32; ++k) d += hr[k] * p[k];
    float v = tanhf(d / sqrtf(nn));
    unsigned int u = __float_as_uint(v);
    if (u == 0x80000000u) u = 0u;                 // normalize -0.0
    ordv = (u & 0x80000000u) ? ~u : (u | 0x80000000u);
    inv[b * M + t] = -1;
  } else {
    ordv = 0u;                                     // sorts last
  }
  skey[t] = ((unsigned long long)(~ordv) << 32) | (unsigned int)t;
  __syncthreads();
  for (int k = 2; k <= MPAD; k <<= 1) {
    for (int j = k >> 1; j > 0; j >>= 1) {
      int ixj = t ^ j;
      if (ixj > t) {
        unsigned long long a = skey[t], c = skey[ixj];
        bool up = ((t & k) == 0);
        if (up == (a > c)) { skey[t] = c; skey[ixj] = a; }
      }
      __syncthreads();
    }
  }
  if (t < K) {
    unsigned long long kk = skey[t];
    unsigned int ord = ~(unsigned int)(kk >> 32);
    unsigned int u = (ord & 0x80000000u) ? (ord & 0x7FFFFFFFu) : ~ord;
    int idx = (int)(kk & 0xFFFFFFFFull);
    perm[b * K + t] = idx;
    vals[b * K + t] = __uint_as_float(u);
    inv[b * M + idx] = t;
  }
}

// ---------------- A1 = augment(adj)[perm1,perm1] via bitsets ---------------
__global__ void k_buildA1(const unsigned long long* __restrict__ mask,
                          const int* __restrict__ perm1, float* __restrict__ A1,
                          float* __restrict__ dis1) {
  __shared__ unsigned long long smT[16 * KK1];   // transposed: smT[w*KK1 + j]
  __shared__ int sp[KK1];
  int blk = blockIdx.x;
  int b = blk / 52, chunk = blk - b * 52;
  int t = threadIdx.x;
  if (t < KK1) sp[t] = perm1[b * KK1 + t];
  __syncthreads();
  for (int q = t; q < KK1 * 16; q += 256) {
    int i = q >> 4, w = q & 15;
    smT[w * KK1 + i] = mask[((size_t)(b * NN + sp[i])) * 16 + w];
  }
  __syncthreads();
  int wave = t >> 6, lane = t & 63;
  int i = chunk * 4 + wave;
  if (i < KK1) {
    unsigned long long r[16];
#pragma unroll
    for (int w = 0; w < 16; ++w) r[w] = smT[w * KK1 + i];
    float rowsum = 0.f;
    for (int j = lane; j < KK1; j += 64) {
      int cnt = 0;
#pragma unroll
      for (int w = 0; w < 16; ++w) cnt += __popcll(r[w] & smT[w * KK1 + j]);
      int pj = sp[j];
      float edge = (float)((r[pj >> 6] >> (pj & 63)) & 1ull);
      float v = (j == i) ? 0.f : ((float)cnt + 2.f * edge);
      A1[((size_t)(b * KK1) + i) * KK1 + j] = v;
      rowsum += v;
    }
#pragma unroll
    for (int o = 32; o; o >>= 1) rowsum += __shfl_xor(rowsum, o);
    if (lane == 0) dis1[b * KK1 + i] = rsqrtf(rowsum + 2.0f);
  }
}

// ------- t = dis * ((h[perm]*val) @ W)  (gather fused; val factored out) ---
__global__ void k_xw32g(const float* __restrict__ h, const int* __restrict__ perm,
                        const float* __restrict__ vals, const float* __restrict__ W,
                        const float* __restrict__ dis, int M, int K,
                        float* __restrict__ out) {
  int idx = blockIdx.x * 256 + threadIdx.x;       // BB*K*32
  int f = idx & 31; int q = idx >> 5;             // q = b*K + k
  int b = q / K;
  int src = perm[q];
  const float* xr = h + (size_t)(b * M + src) * 32;
  float s = 0.f;
#pragma unroll
  for (int k = 0; k < 32; ++k) s += xr[k] * W[k * 32 + f];
  out[idx] = s * dis[q] * vals[q];
}

// ------- t = dis * ((h + unpool(up)) @ W)  (scatter-add fused via inv) -----
__global__ void k_xw32u(const float* __restrict__ h, const float* __restrict__ up,
                        const int* __restrict__ inv, const float* __restrict__ W,
                        const float* __restrict__ dis, int M, int K,
                        float* __restrict__ out) {
  int idx = blockIdx.x * 256 + threadIdx.x;       // rows*32
  int f = idx & 31; int node = idx >> 5;          // node = b*M + i
  int b = node / M;
  int iv = inv[node];
  const float* xr = h + (size_t)node * 32;
  float s = 0.f;
  if (iv >= 0) {
    const float* ur = up + (size_t)(b * K + iv) * 32;
#pragma unroll
    for (int k = 0; k < 32; ++k) s += (xr[k] + ur[k]) * W[k * 32 + f];
  } else {
#pragma unroll
    for (int k = 0; k < 32; ++k) s += xr[k] * W[k * 32 + f];
  }
  out[idx] = s * dis[node];
}

// ---------------- dense GCN apply: one block per row, 8-way K split --------
template<bool RELU>
__global__ __launch_bounds__(256) void k_dense_apply(
    const float* __restrict__ A, const float* __restrict__ t,
    const float* __restrict__ dis, const float* __restrict__ bias,
    int M, float* __restrict__ out) {
  int row = blockIdx.x;
  int b = row / M, i = row - b * M;
  int tid = threadIdx.x;
  int g = tid >> 5, f = tid & 31;
  const float* Ar = A + (size_t)row * M;
  const float* tb = t + (size_t)b * M * 32;
  float acc = 0.f;
  for (int j = g; j < M; j += 8)
    acc += Ar[j] * tb[j * 32 + f];
  __shared__ float ls[8][32];
  ls[g][f] = acc;
  __syncthreads();
  if (tid < 32) {
    float s = 0.f;
#pragma unroll
    for (int q = 0; q < 8; ++q) s += ls[q][tid];
    s += 2.0f * tb[i * 32 + tid];
    float r = dis[row] * s + bias[tid];
    if (RELU) r = fmaxf(r, 0.f);
    out[(size_t)row * 32 + tid] = r;
  }
}

// ---------------- A2 = augment(A1)[perm2,perm2] + fused dis2 ---------------
__global__ void k_buildA2(const float* __restrict__ A1, const int* __restrict__ perm2,
                          float* __restrict__ A2, float* __restrict__ dis2) {
  __shared__ float gsum[8];
  int row = blockIdx.x;                            // b*KK2 + i
  int b = row / KK2, i = row - b * KK2;
  int g = threadIdx.x >> 5, lane = threadIdx.x & 31;
  int pi = perm2[b * KK2 + i];
  const float* Ri = A1 + ((size_t)(b * KK1 + pi)) * KK1;
  float part = 0.f;
  for (int j = g; j < KK2; j += 8) {
    int pj = perm2[b * KK2 + j];
    const float* Rj = A1 + ((size_t)(b * KK1 + pj)) * KK1;
    float s = 0.f;
    for (int k = lane; k < KK1; k += 32) s += Ri[k] * Rj[k];
#pragma unroll
    for (int o = 16; o; o >>= 1) s += __shfl_xor(s, o, 32);
    float v = (i == j) ? 0.f : (s + 2.0f * Ri[pj]);
    if (lane == 0) {
      A2[((size_t)(b * KK2) + i) * KK2 + j] = v;
      part += v;
    }
  }
  if (lane == 0) gsum[g] = part;
  __syncthreads();
  if (threadIdx.x == 0) {
    float s = 0.f;
#pragma unroll
    for (int q = 0; q < 8; ++q) s += gsum[q];
    dis2[row] = rsqrtf(s + 2.0f);
  }
}

// ------- batchnorm partial stats: per-block slots, no atomics, no memset ---
__global__ void k_bnstats(const float* __restrict__ h, float* __restrict__ pacc) {
  int t = threadIdx.x;
  int f = t & 31, g = t >> 5;                      // 8 row-groups
  int rowBase = blockIdx.x * 128;
  float s = 0.f, sq = 0.f;
  for (int r = g; r < 128; r += 8) {
    float v = h[(size_t)(rowBase + r) * 32 + f];
    s += v; sq += v * v;
  }
  __shared__ float ls[8][32], lq[8][32];
  ls[g][f] = s; lq[g][f] = sq;
  __syncthreads();
  if (t < 32) {
    float S = 0.f, Q = 0.f;
#pragma unroll
    for (int i = 0; i < 8; ++i) { S += ls[i][t]; Q += lq[i][t]; }
    pacc[blockIdx.x * 64 + t] = S;
    pacc[blockIdx.x * 64 + 32 + t] = Q;
  }
}

// ---------------- BN + 3-layer MLP head (LDS-staged weights) ---------------
__global__ __launch_bounds__(64) void k_mlp(
    const float* __restrict__ h, const float* __restrict__ pacc,
    const float* __restrict__ gamma, const float* __restrict__ beta,
    const float* __restrict__ W1, const float* __restrict__ b1,
    const float* __restrict__ W2, const float* __restrict__ b2,
    const float* __restrict__ W3, const float* __restrict__ b3,
    float* __restrict__ out) {
  __shared__ float sW1[1024], sW2[1024], sW3[128];
  __shared__ float sb1[32], sb2[32], sb3[4], sscale[32], sshift[32];
  int t = threadIdx.x;
  {
    const float4* W1v = (const float4*)W1; float4* d1 = (float4*)sW1;
#pragma unroll
    for (int i = 0; i < 4; ++i) d1[t + i * 64] = W1v[t + i * 64];
    const float4* W2v = (const float4*)W2; float4* d2 = (float4*)sW2;
#pragma unroll
    for (int i = 0; i < 4; ++i) d2[t + i * 64] = W2v[t + i * 64];
    if (t < 32) ((float4*)sW3)[t] = ((const float4*)W3)[t];
    if (t < 32) { sb1[t] = b1[t]; sb2[t] = b2[t]; }
    if (t < 4) sb3[t] = b3[t];
    if (t < 32) {
      float S = 0.f, Q = 0.f;
      for (int q = 0; q < 128; ++q) { S += pacc[q * 64 + t]; Q += pacc[q * 64 + 32 + t]; }
      const float inv = 1.0f / (float)(BB * NN);
      float m = S * inv;
      float v = Q * inv - m * m;
      float sc = gamma[t] * rsqrtf(v + 1e-5f);
      sscale[t] = sc;
      sshift[t] = beta[t] - m * sc;
    }
  }
  __syncthreads();
  int node = blockIdx.x * 64 + t;
  const float4* hr = (const float4*)(h + (size_t)node * 32);
  float hn[32];
#pragma unroll
  for (int i = 0; i < 8; ++i) {
    float4 x = hr[i];
    hn[i * 4 + 0] = x.x * sscale[i * 4 + 0] + sshift[i * 4 + 0];
    hn[i * 4 + 1] = x.y * sscale[i * 4 + 1] + sshift[i * 4 + 1];
    hn[i * 4 + 2] = x.z * sscale[i * 4 + 2] + sshift[i * 4 + 2];
    hn[i * 4 + 3] = x.w * sscale[i * 4 + 3] + sshift[i * 4 + 3];
  }
  float r1[32];
#pragma unroll
  for (int f = 0; f < 32; ++f) r1[f] = sb1[f];
#pragma unroll
  for (int k = 0; k < 32; ++k) {
    float a = hn[k];
#pragma unroll
    for (int f = 0; f < 32; ++f) r1[f] += a * sW1[k * 32 + f];
  }
#pragma unroll
  for (int f = 0; f < 32; ++f) r1[f] = r1[f] > 0.f ? r1[f] : 0.01f * r1[f];
  float r2[32];
#pragma unroll
  for (int f = 0; f < 32; ++f) r2[f] = sb2[f];
#pragma unroll
  for (int k = 0; k < 32; ++k) {
    float a = r1[k];
#pragma unroll
    for (int f = 0; f < 32; ++f) r2[f] += a * sW2[k * 32 + f];
  }
#pragma unroll
  for (int f = 0; f < 32; ++f) r2[f] = r2[f] > 0.f ? r2[f] : 0.01f * r2[f];
  float r3[4];
#pragma unroll
  for (int c = 0; c < 4; ++c) r3[c] = sb3[c];
#pragma unroll
  for (int k = 0; k < 32; ++k) {
    float a = r2[k];
#pragma unroll
    for (int c = 0; c < 4; ++c) r3[c] += a * sW3[k * 4 + c];
  }
  float4 o;
  o.x = 1.0f / (1.0f + expf(-r3[0]));
  o.y = r3[1]; o.z = r3[2]; o.w = r3[3];
  ((float4*)out)[node] = o;
}

extern "C" void kernel_launch(void* const* d_in, const int* in_sizes, int n_in,
                              void* d_out, int out_size, void* d_ws, size_t ws_size,
                              hipStream_t stream) {
  const float* x    = (const float*)d_in[0];
  const float* adj  = (const float*)d_in[1];
  const float* Wd0  = (const float*)d_in[2];
  const float* bd0  = (const float*)d_in[3];
  const float* Wd1  = (const float*)d_in[4];
  const float* bd1  = (const float*)d_in[5];
  const float* Wd2  = (const float*)d_in[6];
  const float* bd2  = (const float*)d_in[7];
  const float* Wu0  = (const float*)d_in[8];
  const float* bu0  = (const float*)d_in[9];
  const float* Wu1  = (const float*)d_in[10];
  const float* bu1  = (const float*)d_in[11];
  const float* p1   = (const float*)d_in[12];
  const float* p2   = (const float*)d_in[13];
  const float* gamma= (const float*)d_in[14];
  const float* beta = (const float*)d_in[15];
  const float* W1   = (const float*)d_in[16];
  const float* b1   = (const float*)d_in[17];
  const float* W2   = (const float*)d_in[18];
  const float* b2   = (const float*)d_in[19];
  const float* W3   = (const float*)d_in[20];
  const float* b3   = (const float*)d_in[21];
  float* out = (float*)d_out;

  char* w = (char*)d_ws;
  auto alloc = [&](size_t bytes) -> void* {
    void* p = (void*)w;
    w += (bytes + 255) & ~(size_t)255;
    return p;
  };
  float* dis0 = (float*)alloc(BB * NN * 4);
  int*   ncnt = (int*)alloc(BB * NN * 4);
  int*   nbr  = (int*)alloc((size_t)BB * NN * CAP * 4);
  unsigned long long* mask = (unsigned long long*)alloc((size_t)BB * NN * 16 * 8);
  float* dxw  = (float*)alloc((size_t)BB * NN * 32 * 4);
  float* h0   = (float*)alloc((size_t)BB * NN * 32 * 4);
  int*   perm1= (int*)alloc(BB * KK1 * 4);
  float* vals1= (float*)alloc(BB * KK1 * 4);
  int*   inv1 = (int*)alloc(BB * NN * 4);
  float* A1   = (float*)alloc((size_t)BB * KK1 * KK1 * 4);
  float* dis1 = (float*)alloc(BB * KK1 * 4);
  float* t1   = (float*)alloc((size_t)BB * KK1 * 32 * 4);
  float* h1   = (float*)alloc((size_t)BB * KK1 * 32 * 4);
  int*   perm2= (int*)alloc(BB * KK2 * 4);
  float* vals2= (float*)alloc(BB * KK2 * 4);
  int*   inv2 = (int*)alloc(BB * KK1 * 4);
  float* A2   = (float*)alloc((size_t)BB * KK2 * KK2 * 4);
  float* dis2 = (float*)alloc(BB * KK2 * 4);
  float* t2   = (float*)alloc((size_t)BB * KK2 * 32 * 4);
  float* h2   = (float*)alloc((size_t)BB * KK2 * 32 * 4);
  float* hu0  = (float*)alloc((size_t)BB * KK1 * 32 * 4);
  float* hfin = (float*)alloc((size_t)BB * NN * 32 * 4);
  float* pacc = (float*)alloc(128 * 64 * 4);

  const int TOT_N32  = BB * NN * 32;     // 524288
  const int TOT_K132 = BB * KK1 * 32;    // 104960
  const int TOT_K232 = BB * KK2 * 32;    // 21504

  // 1) adj pass: degree + bitmask + CSR + fused x@Wd0
  k_deg_csr<<<BB * NN / 4, 256, 0, stream>>>(adj, x, Wd0, dis0, ncnt, nbr, mask, dxw);
  // 2) GCN0 apply
  k_spmm<true><<<BB * NN / 8, 256, 0, stream>>>(dxw, dis0, ncnt, nbr, bd0, h0);
  // 3) top-k pool 1 (+inv1), A1 (+dis1)
  k_topk<1024><<<BB, 1024, 0, stream>>>(h0, p1, NN, KK1, perm1, vals1, inv1);
  k_buildA1<<<BB * 52, 256, 0, stream>>>(mask, perm1, A1, dis1);
  // 4) GCN1 (gather fused)
  k_xw32g<<<TOT_K132 / 256, 256, 0, stream>>>(h0, perm1, vals1, Wd1, dis1, NN, KK1, t1);
  k_dense_apply<true><<<BB * KK1, 256, 0, stream>>>(A1, t1, dis1, bd1, KK1, h1);
  // 5) top-k pool 2 (+inv2), A2 (+dis2)
  k_topk<256><<<BB, 256, 0, stream>>>(h1, p2, KK1, KK2, perm2, vals2, inv2);
  k_buildA2<<<BB * KK2, 256, 0, stream>>>(A1, perm2, A2, dis2);
  // 6) GCN2 (gather fused)
  k_xw32g<<<TOT_K232 / 256, 256, 0, stream>>>(h1, perm2, vals2, Wd2, dis2, KK1, KK2, t2);
  k_dense_apply<true><<<BB * KK2, 256, 0, stream>>>(A2, t2, dis2, bd2, KK2, h2);
  // 7) up-GCN level-1 (unpool fused via inv2)
  k_xw32u<<<TOT_K132 / 256, 256, 0, stream>>>(h1, h2, inv2, Wu0, dis1, KK1, KK2, t1);
  k_dense_apply<true><<<BB * KK1, 256, 0, stream>>>(A1, t1, dis1, bu0, KK1, hu0);
  // 8) final GCN level-0 (unpool fused via inv1, sparse, no relu)
  k_xw32u<<<TOT_N32 / 256, 256, 0, stream>>>(h0, hu0, inv1, Wu1, dis0, NN, KK1, dxw);
  k_spmm<false><<<BB * NN / 8, 256, 0, stream>>>(dxw, dis0, ncnt, nbr, bu1, hfin);
  // 9) batchnorm partials + fused BN/MLP head
  k_bnstats<<<128, 256, 0, stream>>>(hfin, pacc);
  k_mlp<<<BB * NN / 64, 64, 0, stream>>>(hfin, pacc, gamma, beta,
                                         W1, b1, W2, b2, W3, b3, out);
}